// Round 3
// baseline (686.504 us; speedup 1.0000x reference)
//
#include <hip/hip_runtime.h>
#include <hip/hip_cooperative_groups.h>
#include <math.h>

namespace cg = cooperative_groups;

// ---------------------------------------------------------------------------
// Problem constants (fixed production sizes from the reference)
// ---------------------------------------------------------------------------
namespace {
constexpr int cB  = 64;
constexpr int cNQ = 32;
constexpr int cND = 512;
constexpr int cNd = cB * cND;   // 32768
constexpr int cNq = cB * cNQ;   // 2048
constexpr int cEd = cNd * 8;    // 262144 (exactly 4096 per graph, graph-sorted)
constexpr int cEq = cNq * 8;    // 16384  (exactly 256 per graph, graph-sorted)
constexpr int LD_STRIDE = 516;

// mega-kernel geometry
constexpr int NB = 256;   // persistent blocks (co-residency validated by coop launch)
constexpr int NT = 512;

// phase-1 wave-task counts
constexpr int W_XD = 8192;
constexpr int W_XQ = 512;
constexpr int W_V  = 16;
constexpr int W_CVT = W_XD + W_XQ + 3 * W_V;  // 8752
constexpr int W_TR  = 808;
constexpr int W_TOT = W_CVT + W_TR;           // 9560
constexpr int WSLOTS = (NB - 68) * 8;         // 1504

// fallback (R0) kernel ranges
constexpr int NB_CVT = 2188, NB_T2BF = 808, NB_CNT = (cEd + cEq) / 256;
constexpr int NB_FILL = (cEd + cEq) / 256;
}

#define F4C(p) (*(const float4*)(p))

typedef __attribute__((ext_vector_type(8))) __bf16 bf16x8;
typedef __attribute__((ext_vector_type(4))) float floatx4;

__device__ __forceinline__ ushort f2bf(float f) {
  union { float f; unsigned u; } v;
  v.f = f;
  unsigned u = v.u;
  return (ushort)((u + 0x7fffu + ((u >> 16) & 1u)) >> 16);
}
__device__ __forceinline__ float bf2f(ushort u) {
  union { unsigned u; float f; } v;
  v.u = ((unsigned)u) << 16;
  return v.f;
}
__device__ __forceinline__ float4 us4f4(ushort4 u) {
  return make_float4(bf2f(u.x), bf2f(u.y), bf2f(u.z), bf2f(u.w));
}
__device__ __forceinline__ ushort4 f4us4(float4 f) {
  ushort4 o;
  o.x = f2bf(f.x); o.y = f2bf(f.y); o.z = f2bf(f.z); o.w = f2bf(f.w);
  return o;
}
__device__ __forceinline__ float fexp2(float x) {
#if __has_builtin(__builtin_amdgcn_exp2f)
  return __builtin_amdgcn_exp2f(x);
#else
  return exp2f(x);
#endif
}
__device__ __forceinline__ float frcp(float x) {
#if __has_builtin(__builtin_amdgcn_rcpf)
  return __builtin_amdgcn_rcpf(x);
#else
  return 1.0f / x;
#endif
}
__device__ __forceinline__ float fsigmoid(float z) {
  return frcp(1.0f + fexp2(z * -1.4426950408889634f));
}
__device__ __forceinline__ float fexp(float x) { return fexp2(x * 1.4426950408889634f); }

__device__ __forceinline__ int swz_g(int j) { return (((j >> 3) & 7) << 3) | (j & 7); }

// ===========================================================================
// MEGA KERNEL (cooperative): 11 phases, 10 grid syncs, 1 launch.
// ===========================================================================
struct MP {
  const float *x_d, *x_q;
  const int *src_d, *dst_d, *src_q, *dst_q;
  const float *W1, *W2, *W3, *Wn0, *Wn1, *Wn2, *V0, *V1, *V2;
  const float *b1, *b2, *b3, *bn0, *bn1, *bn2, *cw0, *cw1, *cw2, *w_end, *b_end;
  ushort *xdbf, *xqbf, *w1T, *w2T, *w3T, *wnT0, *wnT1, *wnT2;
  ushort *vnbf0, *vnbf1, *vnbf2;
  int *cnt_d, *cnt_q, *rp_d, *rp_q;
  float *dinv_d, *dinv_q;
  int *col_d, *col_q;
  ushort *htmp, *dbf, *qbf0, *qbf1, *qbf2, *qwbuf;
  float *accb, *out;
};

__global__ __launch_bounds__(512, 2) void k_mega(MP P) {
  cg::grid_group grid = cg::this_grid();
  __shared__ __align__(16) char SM[34816];
  const int tid = threadIdx.x;
  const int rb = blockIdx.x;
  const int wave = tid >> 6, lane = tid & 63;
  const int col = lane & 15, quad = lane >> 4;
  const int t256 = tid & 255;
  const int sub = rb * 2 + (tid >> 8);  // 256-thread sub-block id in [0,512)

  // ============================ PHASE 1 ====================================
  if (rb < 64) {
    // per-graph data CSR build: 512 nodes, 4096 edges, 512 threads
    int g = rb;
    const int* dstg = P.dst_d + g * 4096;
    const int* srcg = P.src_d + g * 4096;
    int nbase = g * 512;
    int* s_cnt = (int*)SM;
    int* s_base = (int*)(SM + 2048);
    int* s_cur = (int*)(SM + 4096);
    s_cnt[tid] = 0;
    __syncthreads();
    for (int e = tid; e < 4096; e += 512) atomicAdd(&s_cnt[dstg[e] - nbase], 1);
    __syncthreads();
    int v = s_cnt[tid];
    s_base[tid] = v;
    __syncthreads();
    for (int off = 1; off < 512; off <<= 1) {
      int a = (tid >= off) ? s_base[tid - off] : 0;
      __syncthreads();
      s_base[tid] += a;
      __syncthreads();
    }
    int excl = s_base[tid] - v;
    P.cnt_d[nbase + tid] = v;
    P.rp_d[nbase + tid] = g * 4096 + excl;
    P.dinv_d[nbase + tid] = 1.0f / sqrtf((float)(v + 1));
    s_base[tid] = excl;
    s_cur[tid] = 0;
    __syncthreads();
    for (int e = tid; e < 4096; e += 512) {
      int d = dstg[e] - nbase;
      int p = atomicAdd(&s_cur[d], 1);
      P.col_d[g * 4096 + s_base[d] + p] = srcg[e];
    }
  } else if (rb < 68) {
    // per-graph query CSR build: 16 graphs per block, 32 lanes each
    int lg = tid >> 5, l32 = tid & 31;
    int g = (rb - 64) * 16 + lg;
    const int* dstg = P.dst_q + g * 256;
    const int* srcg = P.src_q + g * 256;
    int nbase = g * 32;
    int* s_cnt = (int*)SM;
    int* s_base = (int*)(SM + 2048);
    int* s_cur = (int*)(SM + 4096);
    s_cnt[tid] = 0;
    __syncthreads();
#pragma unroll
    for (int j = 0; j < 8; ++j)
      atomicAdd(&s_cnt[lg * 32 + (dstg[l32 + j * 32] - nbase)], 1);
    __syncthreads();
    int v = s_cnt[tid];
    int incl = v;
#pragma unroll
    for (int off = 1; off < 32; off <<= 1) {
      int a = __shfl_up(incl, off, 32);
      if (l32 >= off) incl += a;
    }
    int excl = incl - v;
    P.cnt_q[nbase + l32] = v;
    P.rp_q[nbase + l32] = g * 256 + excl;
    P.dinv_q[nbase + l32] = 1.0f / sqrtf((float)(v + 1));
    s_base[tid] = excl;
    s_cur[tid] = 0;
    __syncthreads();
#pragma unroll
    for (int j = 0; j < 8; ++j) {
      int e = l32 + j * 32;
      int d = dstg[e] - nbase;
      int p = atomicAdd(&s_cur[lg * 32 + d], 1);
      P.col_q[g * 256 + s_base[lg * 32 + d] + p] = srcg[e];
    }
  } else {
    // barrier-free wave tasks: bf16 conversions + 32x32 transposes
    int wslot = (rb - 68) * 8 + wave;
    for (int t = wslot; t < W_TOT; t += WSLOTS) {
      if (t < W_CVT) {
        const float* srcp;
        ushort* dstp;
        int u;
        if (t < W_XD) { srcp = P.x_d; dstp = P.xdbf; u = t * 64 + lane; }
        else if (t < W_XD + W_XQ) { srcp = P.x_q; dstp = P.xqbf; u = (t - W_XD) * 64 + lane; }
        else if (t < W_XD + W_XQ + W_V) { srcp = P.V0; dstp = P.vnbf0; u = (t - W_XD - W_XQ) * 64 + lane; }
        else if (t < W_XD + W_XQ + 2 * W_V) { srcp = P.V1; dstp = P.vnbf1; u = (t - W_XD - W_XQ - W_V) * 64 + lane; }
        else { srcp = P.V2; dstp = P.vnbf2; u = (t - W_XD - W_XQ - 2 * W_V) * 64 + lane; }
        *(ushort4*)(dstp + (size_t)u * 4) = f4us4(F4C(srcp + (size_t)u * 4));
      } else {
        int tt = t - W_CVT;
        const float* in;
        ushort* ow;
        int R, C, bt, tx;
        if (tt < 8)        { in = P.W1;  ow = P.w1T;  R = 64;  C = 128; bt = 0; tx = tt; }
        else if (tt < 24)  { in = P.W2;  ow = P.w2T;  R = 128; C = 128; bt = 0; tx = tt - 8; }
        else if (tt < 40)  { in = P.W3;  ow = P.w3T;  R = 128; C = 128; bt = 0; tx = tt - 24; }
        else if (tt < 296) { in = P.Wn0; ow = P.wnT0; R = 128; C = 128; bt = (tt - 40) >> 4;  tx = (tt - 40) & 15; }
        else if (tt < 552) { in = P.Wn1; ow = P.wnT1; R = 128; C = 128; bt = (tt - 296) >> 4; tx = (tt - 296) & 15; }
        else               { in = P.Wn2; ow = P.wnT2; R = 128; C = 128; bt = (tt - 552) >> 4; tx = (tt - 552) & 15; }
        int tilesC = C >> 5;
        int tr = tx / tilesC, tc = tx - tr * tilesC;
        const float* ib = in + (size_t)bt * R * C;
        ushort* ob = ow + (size_t)bt * R * C;
        float* tw = (float*)(SM + wave * 4224);
        int lx = lane & 31, lh = lane >> 5;
#pragma unroll
        for (int i = 0; i < 16; ++i) {
          int r = lh + 2 * i;
          tw[r * 33 + lx] = ib[(size_t)(tr * 32 + r) * C + tc * 32 + lx];
        }
        asm volatile("s_waitcnt lgkmcnt(0)" ::: "memory");
#pragma unroll
        for (int i = 0; i < 16; ++i) {
          int c = lh + 2 * i;
          ob[(size_t)(tc * 32 + c) * R + tr * 32 + lx] = f2bf(tw[lx * 33 + c]);
        }
        asm volatile("s_waitcnt lgkmcnt(0)" ::: "memory");
      }
    }
  }
  grid.sync();

  // ============================ PHASE 2: GEMM layer 1 (KD=64) ==============
  {
    int w4 = t256 >> 6;
    for (int s = sub; s < 544; s += 512) {
      bool isQ = s >= 512;
      int node0;
      if (isQ) node0 = (s - 512) * 64;
      else node0 = swz_g(s) * 512 + (s >> 6) * 64;
      int mloc = node0 + w4 * 16;
      const ushort* X = isQ ? P.xqbf : P.xdbf;
      const float* dv = isQ ? P.dinv_q : P.dinv_d;
      size_t hbase = isQ ? (size_t)cNd : 0;
      floatx4 acc[8];
#pragma unroll
      for (int ct = 0; ct < 8; ++ct)
#pragma unroll
        for (int r = 0; r < 4; ++r) acc[ct][r] = 0.0f;
#pragma unroll
      for (int kc = 0; kc < 2; ++kc) {
        bf16x8 a = *(const bf16x8*)(X + (size_t)(mloc + col) * 64 + kc * 32 + quad * 8);
#pragma unroll
        for (int ct = 0; ct < 8; ++ct) {
          bf16x8 b = *(const bf16x8*)(P.w1T + (size_t)(ct * 16 + col) * 64 + kc * 32 + quad * 8);
          acc[ct] = __builtin_amdgcn_mfma_f32_16x16x32_bf16(a, b, acc[ct], 0, 0, 0);
        }
      }
      float sc[4];
#pragma unroll
      for (int r = 0; r < 4; ++r) sc[r] = dv[mloc + quad * 4 + r];
#pragma unroll
      for (int ct = 0; ct < 8; ++ct)
#pragma unroll
        for (int r = 0; r < 4; ++r)
          P.htmp[(hbase + mloc + quad * 4 + r) * 128 + ct * 16 + col] = f2bf(acc[ct][r] * sc[r]);
    }
  }
  grid.sync();

  // ============================ LEVEL LOOP =================================
  for (int l = 0; l < 3; ++l) {
    const ushort* vnbf = l == 0 ? P.vnbf0 : (l == 1 ? P.vnbf1 : P.vnbf2);
    const float* bnl = l == 0 ? P.bn0 : (l == 1 ? P.bn1 : P.bn2);
    const float* cwl = l == 0 ? P.cw0 : (l == 1 ? P.cw1 : P.cw2);
    const ushort* wnTl = l == 0 ? P.wnT0 : (l == 1 ? P.wnT1 : P.wnT2);
    const float* biasl = l == 0 ? P.b1 : (l == 1 ? P.b2 : P.b3);
    ushort* qbfl = l == 0 ? P.qbf0 : (l == 1 ? P.qbf1 : P.qbf2);
    const ushort* gWT = l == 0 ? P.w2T : P.w3T;
    const int o1 = l == 0 ? 0 : (l == 1 ? 19 : 3);
    const int o2 = l == 2 ? 35 : -1;
    const int hasF = l > 0 ? 1 : 0;
    const int do_sm = (l == 1) ? 0 : 1;
    const int mode = l;
    const int widx = l;

    // -------- PHASE 3: GCN aggregate (query tasks first, then data) --------
    {
      int l32 = tid & 31;
      for (int s = sub; s < 4352; s += 512) {
        bool isQ = s < 256;
        int node;
        const int *rp, *cnt, *colv;
        const float* dinv;
        const ushort* hs;
        ushort* outp;
        if (isQ) {
          node = swz_g(s & 63) * 32 + (s >> 6) * 8 + (t256 >> 5);
          rp = P.rp_q; cnt = P.cnt_q; colv = P.col_q; dinv = P.dinv_q;
          hs = P.htmp + (size_t)cNd * 128;
          outp = qbfl;
        } else {
          int j = s - 256;
          node = swz_g(j & 63) * 512 + (j >> 6) * 8 + (t256 >> 5);
          rp = P.rp_d; cnt = P.cnt_d; colv = P.col_d; dinv = P.dinv_d;
          hs = P.htmp;
          outp = P.dbf;
        }
        int c = cnt[node], s0 = rp[node];
        float dt = dinv[node];
        float4 acc = us4f4(*(const ushort4*)(hs + (size_t)node * 128 + l32 * 4));
        int cm = c < 32 ? c : 32;
        for (int j0 = 0; j0 < cm; j0 += 8) {
          int ss[8];
          ushort4 vv[8];
#pragma unroll
          for (int u = 0; u < 8; ++u) {
            int jj = j0 + u;
            ss[u] = (jj < cm) ? colv[s0 + jj] : -1;
          }
#pragma unroll
          for (int u = 0; u < 8; ++u)
            if (ss[u] >= 0) vv[u] = *(const ushort4*)(hs + (size_t)ss[u] * 128 + l32 * 4);
#pragma unroll
          for (int u = 0; u < 8; ++u) {
            if (ss[u] >= 0) {
              float4 f = us4f4(vv[u]);
              acc.x += f.x; acc.y += f.y; acc.z += f.z; acc.w += f.w;
            }
          }
        }
        for (int j2 = 32; j2 < c; ++j2) {
          int s2 = colv[s0 + j2];
          float4 f = us4f4(*(const ushort4*)(hs + (size_t)s2 * 128 + l32 * 4));
          acc.x += f.x; acc.y += f.y; acc.z += f.z; acc.w += f.w;
        }
        float4 bv = F4C(biasl + l32 * 4);
        float4 r;
        r.x = fmaxf(acc.x * dt + bv.x, 0.0f);
        r.y = fmaxf(acc.y * dt + bv.y, 0.0f);
        r.z = fmaxf(acc.z * dt + bv.z, 0.0f);
        r.w = fmaxf(acc.w * dt + bv.w, 0.0f);
        *(ushort4*)(outp + (size_t)node * 128 + l32 * 4) = f4us4(r);
      }
    }
    grid.sync();

    // -------- PHASE 4: qW[b,k] = q[b] @ Wn[k] ------------------------------
    {
      int w4 = t256 >> 6;
      int et0 = w4 * 2;
      for (int s = sub; s < 1024; s += 512) {
        int b = swz_g(s & 63), k = s >> 6;
        floatx4 acc[2][2];
#pragma unroll
        for (int qt = 0; qt < 2; ++qt)
#pragma unroll
          for (int ei = 0; ei < 2; ++ei)
#pragma unroll
            for (int r = 0; r < 4; ++r) acc[qt][ei][r] = 0.0f;
#pragma unroll
        for (int kc = 0; kc < 4; ++kc) {
          bf16x8 a0 = *(const bf16x8*)(qbfl + (size_t)(b * 32 + col) * 128 + kc * 32 + quad * 8);
          bf16x8 a1 = *(const bf16x8*)(qbfl + (size_t)(b * 32 + 16 + col) * 128 + kc * 32 + quad * 8);
#pragma unroll
          for (int ei = 0; ei < 2; ++ei) {
            bf16x8 bf = *(const bf16x8*)(wnTl + (size_t)(k * 128 + (et0 + ei) * 16 + col) * 128 +
                                         kc * 32 + quad * 8);
            acc[0][ei] = __builtin_amdgcn_mfma_f32_16x16x32_bf16(a0, bf, acc[0][ei], 0, 0, 0);
            acc[1][ei] = __builtin_amdgcn_mfma_f32_16x16x32_bf16(a1, bf, acc[1][ei], 0, 0, 0);
          }
        }
#pragma unroll
        for (int qt = 0; qt < 2; ++qt)
#pragma unroll
          for (int ei = 0; ei < 2; ++ei)
#pragma unroll
            for (int r = 0; r < 4; ++r)
              P.qwbuf[((size_t)(b * 16 + k) << 12) + (qt * 16 + quad * 4 + r) * 128 +
                      (et0 + ei) * 16 + col] = f2bf(acc[qt][ei][r]);
      }
    }
    grid.sync();

    // -------- PHASE 5: fused NTN level (blocks 0..127) + next GEMM ---------
    if (rb < 128) {
      float* s_ld = (float*)SM;
      float* s_lq = (float*)(SM + 33024);
      float* s_red = (float*)(SM + 34048);
      int b = swz_g(rb & 63);
      int qh = rb >> 6;
      int n0 = wave * 64;

      bf16x8 bfr[4][4];
#pragma unroll
      for (int s = 0; s < 4; ++s)
#pragma unroll
        for (int kc = 0; kc < 4; ++kc)
          bfr[s][kc] = *(const bf16x8*)(P.dbf + ((size_t)(b * 512 + n0 + s * 16 + col) << 7) +
                                        kc * 32 + quad * 8);
      bf16x8 aq[4];
#pragma unroll
      for (int kc = 0; kc < 4; ++kc)
        aq[kc] = *(const bf16x8*)(qbfl + (size_t)(b * 32 + qh * 16 + col) * 128 +
                                  kc * 32 + quad * 8);

      floatx4 att[4];
#pragma unroll
      for (int s = 0; s < 4; ++s)
#pragma unroll
        for (int r = 0; r < 4; ++r) att[s][r] = 0.0f;
#pragma unroll
      for (int kc = 0; kc < 4; ++kc)
#pragma unroll
        for (int s = 0; s < 4; ++s)
          att[s] = __builtin_amdgcn_mfma_f32_16x16x32_bf16(aq[kc], bfr[s][kc], att[s], 0, 0, 0);
      const float sc = 0.088388347648318440550f;
#pragma unroll
      for (int s = 0; s < 4; ++s)
#pragma unroll
        for (int r = 0; r < 4; ++r) att[s][r] *= sc;

      {
        bf16x8 vn2[4];
#pragma unroll
        for (int kc = 0; kc < 4; ++kc)
          vn2[kc] = *(const bf16x8*)(vnbf + col * 256 + 128 + kc * 32 + quad * 8);
#pragma unroll
        for (int s = 0; s < 4; ++s) {
          floatx4 lda;
#pragma unroll
          for (int r = 0; r < 4; ++r) lda[r] = 0.0f;
#pragma unroll
          for (int kc = 0; kc < 4; ++kc)
            lda = __builtin_amdgcn_mfma_f32_16x16x32_bf16(bfr[s][kc], vn2[kc], lda, 0, 0, 0);
#pragma unroll
          for (int r = 0; r < 4; ++r)
            s_ld[col * LD_STRIDE + n0 + s * 16 + quad * 4 + r] = lda[r];
        }
      }
      if (wave == 0) {
        bf16x8 vn1[4];
#pragma unroll
        for (int kc = 0; kc < 4; ++kc)
          vn1[kc] = *(const bf16x8*)(vnbf + col * 256 + kc * 32 + quad * 8);
        floatx4 lqa;
#pragma unroll
        for (int r = 0; r < 4; ++r) lqa[r] = 0.0f;
#pragma unroll
        for (int kc = 0; kc < 4; ++kc)
          lqa = __builtin_amdgcn_mfma_f32_16x16x32_bf16(aq[kc], vn1[kc], lqa, 0, 0, 0);
#pragma unroll
        for (int r = 0; r < 4; ++r) s_lq[col * 16 + quad * 4 + r] = lqa[r];
      }
      __syncthreads();

      float red[4], M[4];
#pragma unroll
      for (int r = 0; r < 4; ++r) {
        float m = fmaxf(fmaxf(att[0][r], att[1][r]), fmaxf(att[2][r], att[3][r]));
#pragma unroll
        for (int o = 1; o < 16; o <<= 1) m = fmaxf(m, __shfl_xor(m, o, 64));
        red[r] = m;
      }
      if (col == 0)
#pragma unroll
        for (int r = 0; r < 4; ++r) s_red[(quad * 4 + r) * 8 + wave] = red[r];
      __syncthreads();
#pragma unroll
      for (int r = 0; r < 4; ++r) {
        float m = s_red[(quad * 4 + r) * 8];
#pragma unroll
        for (int w = 1; w < 8; ++w) m = fmaxf(m, s_red[(quad * 4 + r) * 8 + w]);
        M[r] = m;
      }
      __syncthreads();
#pragma unroll
      for (int s = 0; s < 4; ++s)
#pragma unroll
        for (int r = 0; r < 4; ++r) att[s][r] = fexp(att[s][r] - M[r]);
#pragma unroll
      for (int r = 0; r < 4; ++r) {
        float m = att[0][r] + att[1][r] + att[2][r] + att[3][r];
#pragma unroll
        for (int o = 1; o < 16; o <<= 1) m += __shfl_xor(m, o, 64);
        red[r] = m;
      }
      if (col == 0)
#pragma unroll
        for (int r = 0; r < 4; ++r) s_red[(quad * 4 + r) * 8 + wave] = red[r];
      __syncthreads();
#pragma unroll
      for (int r = 0; r < 4; ++r) {
        float m = s_red[(quad * 4 + r) * 8];
#pragma unroll
        for (int w = 1; w < 8; ++w) m += s_red[(quad * 4 + r) * 8 + w];
        M[r] = frcp(m);
      }
      __syncthreads();
#pragma unroll
      for (int s = 0; s < 4; ++s)
#pragma unroll
        for (int r = 0; r < 4; ++r) att[s][r] *= M[r];

      floatx4 eacc[4], facc[4];
#pragma unroll
      for (int s = 0; s < 4; ++s)
#pragma unroll
        for (int r = 0; r < 4; ++r) { eacc[s][r] = 0.0f; facc[s][r] = 0.0f; }

#pragma unroll 4
      for (int k = 0; k < 16; ++k) {
        const ushort* qk = P.qwbuf + ((size_t)(b * 16 + k) << 12) + (qh * 16 + col) * 128 + quad * 8;
        bf16x8 a0 = *(const bf16x8*)(qk);
        bf16x8 a1 = *(const bf16x8*)(qk + 32);
        bf16x8 a2 = *(const bf16x8*)(qk + 64);
        bf16x8 a3 = *(const bf16x8*)(qk + 96);
        floatx4 bil[4];
#pragma unroll
        for (int s = 0; s < 4; ++s) {
#pragma unroll
          for (int r = 0; r < 4; ++r) bil[s][r] = 0.0f;
          bil[s] = __builtin_amdgcn_mfma_f32_16x16x32_bf16(a0, bfr[s][0], bil[s], 0, 0, 0);
          bil[s] = __builtin_amdgcn_mfma_f32_16x16x32_bf16(a1, bfr[s][1], bil[s], 0, 0, 0);
          bil[s] = __builtin_amdgcn_mfma_f32_16x16x32_bf16(a2, bfr[s][2], bil[s], 0, 0, 0);
          bil[s] = __builtin_amdgcn_mfma_f32_16x16x32_bf16(a3, bfr[s][3], bil[s], 0, 0, 0);
        }
        float bnk = bnl[k], cwk = cwl[k];
        float wkk = 0.0f;
        if (hasF) {
          wkk = P.w_end[o1 + k];
          if (o2 >= 0) wkk += P.w_end[o2 + k];
        }
        float lqv[4];
#pragma unroll
        for (int r = 0; r < 4; ++r) lqv[r] = s_lq[k * 16 + quad * 4 + r] + bnk;
#pragma unroll
        for (int s = 0; s < 4; ++s) {
          float ldv = s_ld[k * LD_STRIDE + n0 + s * 16 + col];
#pragma unroll
          for (int r = 0; r < 4; ++r) {
            float sg = fsigmoid(bil[s][r] + lqv[r] + ldv);
            eacc[s][r] += cwk * sg;
            facc[s][r] += wkk * sg;
          }
        }
      }

#pragma unroll
      for (int s = 0; s < 4; ++s)
#pragma unroll
        for (int r = 0; r < 4; ++r) {
          eacc[s][r] *= att[s][r];
          facc[s][r] *= att[s][r];
        }
      if (do_sm) {
#pragma unroll
        for (int r = 0; r < 4; ++r) {
          float m = fmaxf(fmaxf(eacc[0][r], eacc[1][r]), fmaxf(eacc[2][r], eacc[3][r]));
#pragma unroll
          for (int o = 1; o < 16; o <<= 1) m = fmaxf(m, __shfl_xor(m, o, 64));
          red[r] = m;
        }
        if (col == 0)
#pragma unroll
          for (int r = 0; r < 4; ++r) s_red[(quad * 4 + r) * 8 + wave] = red[r];
        __syncthreads();
#pragma unroll
        for (int r = 0; r < 4; ++r) {
          float m = s_red[(quad * 4 + r) * 8];
#pragma unroll
          for (int w = 1; w < 8; ++w) m = fmaxf(m, s_red[(quad * 4 + r) * 8 + w]);
          M[r] = m;
        }
        __syncthreads();
#pragma unroll
        for (int s = 0; s < 4; ++s)
#pragma unroll
          for (int r = 0; r < 4; ++r) eacc[s][r] = fexp(eacc[s][r] - M[r]);
#pragma unroll
        for (int r = 0; r < 4; ++r) {
          float m = eacc[0][r] + eacc[1][r] + eacc[2][r] + eacc[3][r];
#pragma unroll
          for (int o = 1; o < 16; o <<= 1) m += __shfl_xor(m, o, 64);
          red[r] = m;
        }
        if (col == 0)
#pragma unroll
          for (int r = 0; r < 4; ++r) s_red[(quad * 4 + r) * 8 + wave] = red[r];
        __syncthreads();
#pragma unroll
        for (int r = 0; r < 4; ++r) {
          float m = s_red[(quad * 4 + r) * 8];
#pragma unroll
          for (int w = 1; w < 8; ++w) m += s_red[(quad * 4 + r) * 8 + w];
          M[r] = frcp(m);
        }
        __syncthreads();
#pragma unroll
        for (int s = 0; s < 4; ++s)
#pragma unroll
          for (int r = 0; r < 4; ++r) eacc[s][r] *= M[r];
      }
      float wE = P.w_end[widx];
#pragma unroll
      for (int s = 0; s < 4; ++s)
#pragma unroll
        for (int r = 0; r < 4; ++r) eacc[s][r] = wE * eacc[s][r] + (hasF ? facc[s][r] : 0.0f);

      if (mode == 0) {
#pragma unroll
        for (int s = 0; s < 4; ++s)
#pragma unroll
          for (int r = 0; r < 4; ++r)
            P.accb[((size_t)(b * 32 + qh * 16 + quad * 4 + r) << 9) + n0 + s * 16 + col] =
                eacc[s][r];
      } else if (mode == 1) {
#pragma unroll
        for (int s = 0; s < 4; ++s)
#pragma unroll
          for (int r = 0; r < 4; ++r)
            P.accb[((size_t)(b * 32 + qh * 16 + quad * 4 + r) << 9) + n0 + s * 16 + col] +=
                eacc[s][r];
      } else {
        float be = P.b_end[0];
#pragma unroll
        for (int s = 0; s < 4; ++s)
#pragma unroll
          for (int r = 0; r < 4; ++r)
            eacc[s][r] += P.accb[((size_t)(b * 32 + qh * 16 + quad * 4 + r) << 9) +
                                 n0 + s * 16 + col] + be;
#pragma unroll
        for (int r = 0; r < 4; ++r) {
          float m = fmaxf(fmaxf(eacc[0][r], eacc[1][r]), fmaxf(eacc[2][r], eacc[3][r]));
#pragma unroll
          for (int o = 1; o < 16; o <<= 1) m = fmaxf(m, __shfl_xor(m, o, 64));
          red[r] = m;
        }
        if (col == 0)
#pragma unroll
          for (int r = 0; r < 4; ++r) s_red[(quad * 4 + r) * 8 + wave] = red[r];
        __syncthreads();
#pragma unroll
        for (int r = 0; r < 4; ++r) {
          float m = s_red[(quad * 4 + r) * 8];
#pragma unroll
          for (int w2 = 1; w2 < 8; ++w2) m = fmaxf(m, s_red[(quad * 4 + r) * 8 + w2]);
          M[r] = m;
        }
        __syncthreads();
#pragma unroll
        for (int s = 0; s < 4; ++s)
#pragma unroll
          for (int r = 0; r < 4; ++r) eacc[s][r] = fexp(eacc[s][r] - M[r]);
#pragma unroll
        for (int r = 0; r < 4; ++r) {
          float m = eacc[0][r] + eacc[1][r] + eacc[2][r] + eacc[3][r];
#pragma unroll
          for (int o = 1; o < 16; o <<= 1) m += __shfl_xor(m, o, 64);
          red[r] = m;
        }
        if (col == 0)
#pragma unroll
          for (int r = 0; r < 4; ++r) s_red[(quad * 4 + r) * 8 + wave] = red[r];
        __syncthreads();
#pragma unroll
        for (int r = 0; r < 4; ++r) {
          float m = s_red[(quad * 4 + r) * 8];
#pragma unroll
          for (int w2 = 1; w2 < 8; ++w2) m += s_red[(quad * 4 + r) * 8 + w2];
          M[r] = frcp(m);
        }
#pragma unroll
        for (int s = 0; s < 4; ++s)
#pragma unroll
          for (int r = 0; r < 4; ++r)
            P.out[((size_t)(b * 32 + qh * 16 + quad * 4 + r) << 9) + n0 + s * 16 + col] =
                eacc[s][r] * M[r];
      }
    } else if (l < 2) {
      // next-layer GCN GEMM KD=128 (272 tasks over blocks 128..255)
      for (int t = rb - 128; t < 272; t += 128) {
        bool isQ = t >= 256;
        int node0;
        if (isQ) node0 = (t - 256) * 128;
        else node0 = swz_g(t & 63) * 512 + (t >> 6) * 128;
        int mloc = node0 + wave * 16;
        const ushort* X = isQ ? qbfl : P.dbf;
        const float* dv = isQ ? P.dinv_q : P.dinv_d;
        size_t hbase = isQ ? (size_t)cNd : 0;
        floatx4 acc[8];
#pragma unroll
        for (int ct = 0; ct < 8; ++ct)
#pragma unroll
          for (int r = 0; r < 4; ++r) acc[ct][r] = 0.0f;
#pragma unroll
        for (int kc = 0; kc < 4; ++kc) {
          bf16x8 a = *(const bf16x8*)(X + (size_t)(mloc + col) * 128 + kc * 32 + quad * 8);
#pragma unroll
          for (int ct = 0; ct < 8; ++ct) {
            bf16x8 b = *(const bf16x8*)(gWT + (size_t)(ct * 16 + col) * 128 + kc * 32 + quad * 8);
            acc[ct] = __builtin_amdgcn_mfma_f32_16x16x32_bf16(a, b, acc[ct], 0, 0, 0);
          }
        }
        float sc2[4];
#pragma unroll
        for (int r = 0; r < 4; ++r) sc2[r] = dv[mloc + quad * 4 + r];
#pragma unroll
        for (int ct = 0; ct < 8; ++ct)
#pragma unroll
          for (int r = 0; r < 4; ++r)
            P.htmp[(hbase + mloc + quad * 4 + r) * 128 + ct * 16 + col] = f2bf(acc[ct][r] * sc2[r]);
      }
    }
    if (l < 2) grid.sync();
  }
}

// ===========================================================================
// FALLBACK PATH — byte-identical to the verified R0 pipeline (300 µs).
// Used only if the cooperative launch is rejected by the runtime.
// ===========================================================================
__global__ __launch_bounds__(256) void k_front(
    const float* __restrict__ xd, const float* __restrict__ xq,
    const float* __restrict__ v0, const float* __restrict__ v1,
    const float* __restrict__ v2, ushort* __restrict__ oxd, ushort* __restrict__ oxq,
    ushort* __restrict__ ov0, ushort* __restrict__ ov1, ushort* __restrict__ ov2,
    const float* __restrict__ W1, const float* __restrict__ W2,
    const float* __restrict__ W3, const float* __restrict__ Wn0,
    const float* __restrict__ Wn1, const float* __restrict__ Wn2,
    ushort* __restrict__ o1, ushort* __restrict__ o2, ushort* __restrict__ o3,
    ushort* __restrict__ on0, ushort* __restrict__ on1, ushort* __restrict__ on2,
    const int* __restrict__ dst_d, const int* __restrict__ dst_q,
    int* __restrict__ cnt_d, int* __restrict__ cnt_q) {
  __shared__ float tile[32][33];
  int blk = blockIdx.x, tid = threadIdx.x;
  if (blk < NB_CVT) {
    const float* src;
    ushort* dst;
    int i;
    if (blk < 2048) { src = xd; dst = oxd; i = blk * 256 + tid; }
    else if (blk < 2176) { src = xq; dst = oxq; i = (blk - 2048) * 256 + tid; }
    else if (blk < 2180) { src = v0; dst = ov0; i = (blk - 2176) * 256 + tid; }
    else if (blk < 2184) { src = v1; dst = ov1; i = (blk - 2180) * 256 + tid; }
    else { src = v2; dst = ov2; i = (blk - 2184) * 256 + tid; }
    *(ushort4*)(dst + (size_t)i * 4) = f4us4(F4C(src + (size_t)i * 4));
  } else if (blk < NB_CVT + NB_T2BF) {
    int b5 = blk - NB_CVT;
    const float* in;
    ushort* out;
    int R, C, bt, t;
    if (b5 < 8)        { in = W1;  out = o1;  R = 64;  C = 128; bt = 0; t = b5; }
    else if (b5 < 24)  { in = W2;  out = o2;  R = 128; C = 128; bt = 0; t = b5 - 8; }
    else if (b5 < 40)  { in = W3;  out = o3;  R = 128; C = 128; bt = 0; t = b5 - 24; }
    else if (b5 < 296) { in = Wn0; out = on0; R = 128; C = 128; bt = (b5 - 40) >> 4;  t = (b5 - 40) & 15; }
    else if (b5 < 552) { in = Wn1; out = on1; R = 128; C = 128; bt = (b5 - 296) >> 4; t = (b5 - 296) & 15; }
    else               { in = Wn2; out = on2; R = 128; C = 128; bt = (b5 - 552) >> 4; t = (b5 - 552) & 15; }
    int tilesC = C >> 5;
    int tr = t / tilesC, tc = t - tr * tilesC;
    int tx = tid & 31, ty = tid >> 5;
    const float* ib = in + (size_t)bt * R * C;
    ushort* ob = out + (size_t)bt * R * C;
#pragma unroll
    for (int i = 0; i < 4; ++i)
      tile[ty + i * 8][tx] = ib[(tr * 32 + ty + i * 8) * C + tc * 32 + tx];
    __syncthreads();
#pragma unroll
    for (int i = 0; i < 4; ++i)
      ob[(size_t)(tc * 32 + ty + i * 8) * R + tr * 32 + tx] = f2bf(tile[tx][ty + i * 8]);
  } else {
    int i = (blk - NB_CVT - NB_T2BF) * 256 + tid;
    if (i < cEd) atomicAdd(&cnt_d[dst_d[i]], 1);
    else atomicAdd(&cnt_q[dst_q[i - cEd]], 1);
  }
}

__global__ __launch_bounds__(512) void k_scan_dinv(
    const int* __restrict__ cnt_d, const int* __restrict__ cnt_q,
    int* __restrict__ rp_d, int* __restrict__ rp_q,
    float* __restrict__ dinv_d, float* __restrict__ dinv_q) {
  __shared__ int sh[512];
  int blk = blockIdx.x, tid = threadIdx.x;
  if (blk < 64) {
    int v = cnt_d[blk * 512 + tid];
    sh[tid] = v;
    __syncthreads();
    for (int off = 1; off < 512; off <<= 1) {
      int t = (tid >= off) ? sh[tid - off] : 0;
      __syncthreads();
      sh[tid] += t;
      __syncthreads();
    }
    rp_d[blk * 512 + tid] = blk * 4096 + sh[tid] - v;
  } else if (blk < 68) {
    int g = (blk - 64) * 16 + (tid >> 5);
    int lane32 = tid & 31;
    int v = cnt_q[g * 32 + lane32];
    int incl = v;
#pragma unroll
    for (int off = 1; off < 32; off <<= 1) {
      int t = __shfl_up(incl, off, 32);
      if (lane32 >= off) incl += t;
    }
    rp_q[g * 32 + lane32] = g * 256 + incl - v;
  } else {
    int i = (blk - 68) * 512 + tid;
    if (i < cNd) dinv_d[i] = 1.0f / sqrtf((float)(cnt_d[i] + 1));
    else dinv_q[i - cNd] = 1.0f / sqrtf((float)(cnt_q[i - cNd] + 1));
  }
}

__global__ __launch_bounds__(256) void k_fill_gemm1(
    const int* __restrict__ src_d, const int* __restrict__ dst_d,
    const int* __restrict__ src_q, const int* __restrict__ dst_q,
    const int* __restrict__ rp_d, const int* __restrict__ rp_q,
    int* __restrict__ cur_d, int* __restrict__ cur_q, int* __restrict__ col_d,
    int* __restrict__ col_q, const ushort* __restrict__ xdbf,
    const ushort* __restrict__ xqbf, const ushort* __restrict__ w1T,
    const float* __restrict__ dinv_d, const float* __restrict__ dinv_q,
    ushort* __restrict__ htmp) {
  int blk = blockIdx.x, tid = threadIdx.x;
  if (blk < NB_FILL) {
    int i = blk * 256 + tid;
    if (i < cEd) {
      int d = dst_d[i];
      int p = atomicAdd(&cur_d[d], 1);
      col_d[rp_d[d] + p] = src_d[i];
    } else {
      int j = i - cEd;
      int d = dst_q[j];
      int p = atomicAdd(&cur_q[d], 1);
      col_q[rp_q[d] + p] = src_q[j];
    }
    return;
  }
  int blk2 = blk - NB_FILL;
  int wave = tid >> 6, lane = tid & 63;
  int col = lane & 15, quad = lane >> 4;
  bool isQ = blk2 >= 512;
  int node0;
  if (isQ) node0 = (blk2 - 512) * 64;
  else node0 = swz_g(blk2) * 512 + (blk2 >> 6) * 64;
  int mloc = node0 + wave * 16;
  const ushort* X = isQ ? xqbf : xdbf;
  const float* dv = isQ ? dinv_q : dinv_d;
  size_t hbase = isQ ? (size_t)cNd : 0;
  floatx4 acc[8];
#pragma unroll
  for (int ct = 0; ct < 8; ++ct)
#pragma unroll
    for (int r = 0; r < 4; ++r) acc[ct][r] = 0.0f;
#pragma unroll
  for (int kc = 0; kc < 2; ++kc) {
    bf16x8 a = *(const bf16x8*)(X + (size_t)(mloc + col) * 64 + kc * 32 + quad * 8);
#pragma unroll
    for (int ct = 0; ct < 8; ++ct) {
      bf16x8 b = *(const bf16x8*)(w1T + (size_t)(ct * 16 + col) * 64 + kc * 32 + quad * 8);
      acc[ct] = __builtin_amdgcn_mfma_f32_16x16x32_bf16(a, b, acc[ct], 0, 0, 0);
    }
  }
  float sc[4];
#pragma unroll
  for (int r = 0; r < 4; ++r) sc[r] = dv[mloc + quad * 4 + r];
#pragma unroll
  for (int ct = 0; ct < 8; ++ct)
#pragma unroll
    for (int r = 0; r < 4; ++r)
      htmp[(hbase + mloc + quad * 4 + r) * 128 + ct * 16 + col] = f2bf(acc[ct][r] * sc[r]);
}

__global__ __launch_bounds__(256) void gmn_gather_merged(
    const ushort* __restrict__ htmp, const int* __restrict__ rp_d,
    const int* __restrict__ cnt_d, const int* __restrict__ col_d,
    const float* __restrict__ dinv_d, const int* __restrict__ rp_q,
    const int* __restrict__ cnt_q, const int* __restrict__ col_q,
    const float* __restrict__ dinv_q, const float* __restrict__ bias,
    ushort* __restrict__ dbf, ushort* __restrict__ qbf) {
  int blk = blockIdx.x, tid = threadIdx.x;
  bool isQ = blk >= 4096;
  int node;
  if (isQ) {
    int j = blk - 4096;
    node = swz_g(j) * 32 + (j >> 6) * 8 + (tid >> 5);
  } else {
    node = swz_g(blk) * 512 + (blk >> 6) * 8 + (tid >> 5);
  }
  int l = tid & 31;
  const ushort* hs = htmp + (isQ ? (size_t)cNd * 128 : 0);
  const int* rp = isQ ? rp_q : rp_d;
  const int* cnt = isQ ? cnt_q : cnt_d;
  const int* col = isQ ? col_q : col_d;
  const float* dinv = isQ ? dinv_q : dinv_d;
  ushort* outp = isQ ? qbf : dbf;
  int c = cnt[node], s0 = rp[node];
  float dt = dinv[node];
  float4 acc = us4f4(*(const ushort4*)(hs + (size_t)node * 128 + l * 4));
  int cm = c < 32 ? c : 32;
  for (int j0 = 0; j0 < cm; j0 += 8) {
    int ss[8];
    ushort4 v[8];
#pragma unroll
    for (int t = 0; t < 8; ++t) {
      int jj = j0 + t;
      ss[t] = (jj < cm) ? col[s0 + jj] : -1;
    }
#pragma unroll
    for (int t = 0; t < 8; ++t)
      if (ss[t] >= 0) v[t] = *(const ushort4*)(hs + (size_t)ss[t] * 128 + l * 4);
#pragma unroll
    for (int t = 0; t < 8; ++t) {
      if (ss[t] >= 0) {
        float4 f = us4f4(v[t]);
        acc.x += f.x; acc.y += f.y; acc.z += f.z; acc.w += f.w;
      }
    }
  }
  for (int j = 32; j < c; ++j) {
    int s = col[s0 + j];
    float4 f = us4f4(*(const ushort4*)(hs + (size_t)s * 128 + l * 4));
    acc.x += f.x; acc.y += f.y; acc.z += f.z; acc.w += f.w;
  }
  float4 bv = F4C(bias + l * 4);
  float4 r;
  r.x = fmaxf(acc.x * dt + bv.x, 0.0f);
  r.y = fmaxf(acc.y * dt + bv.y, 0.0f);
  r.z = fmaxf(acc.z * dt + bv.z, 0.0f);
  r.w = fmaxf(acc.w * dt + bv.w, 0.0f);
  *(ushort4*)(outp + (size_t)node * 128 + l * 4) = f4us4(r);
}

__global__ __launch_bounds__(256) void gmn_qw(const ushort* __restrict__ qbf,
                                              const ushort* __restrict__ wnT,
                                              ushort* __restrict__ qw) {
  int blk = blockIdx.x, tid = threadIdx.x;
  int wave = tid >> 6, lane = tid & 63;
  int col = lane & 15, quad = lane >> 4;
  int b = swz_g(blk), k = blk >> 6;
  int et0 = wave * 2;
  floatx4 acc[2][2];
#pragma unroll
  for (int qt = 0; qt < 2; ++qt)
#pragma unroll
    for (int ei = 0; ei < 2; ++ei)
#pragma unroll
      for (int r = 0; r < 4; ++r) acc[qt][ei][r] = 0.0f;
#pragma unroll
  for (int kc = 0; kc < 4; ++kc) {
    bf16x8 a0 = *(const bf16x8*)(qbf + (size_t)(b * 32 + col) * 128 + kc * 32 + quad * 8);
    bf16x8 a1 = *(const bf16x8*)(qbf + (size_t)(b * 32 + 16 + col) * 128 + kc * 32 + quad * 8);
#pragma unroll
    for (int ei = 0; ei < 2; ++ei) {
      bf16x8 bf = *(const bf16x8*)(wnT + (size_t)(k * 128 + (et0 + ei) * 16 + col) * 128 +
                                   kc * 32 + quad * 8);
      acc[0][ei] = __builtin_amdgcn_mfma_f32_16x16x32_bf16(a0, bf, acc[0][ei], 0, 0, 0);
      acc[1][ei] = __builtin_amdgcn_mfma_f32_16x16x32_bf16(a1, bf, acc[1][ei], 0, 0, 0);
    }
  }
#pragma unroll
  for (int qt = 0; qt < 2; ++qt)
#pragma unroll
    for (int ei = 0; ei < 2; ++ei)
#pragma unroll
      for (int r = 0; r < 4; ++r)
        qw[((size_t)(b * 16 + k) << 12) + (qt * 16 + quad * 4 + r) * 128 +
           (et0 + ei) * 16 + col] = f2bf(acc[qt][ei][r]);
}

__global__ __launch_bounds__(512, 2) void k_level_gemm(
    const ushort* __restrict__ qbf, const ushort* __restrict__ dbf,
    const ushort* __restrict__ qw, const ushort* __restrict__ vnbf,
    const float* __restrict__ bn, const float* __restrict__ cw,
    const float* __restrict__ w_end, const float* __restrict__ b_end,
    int o1, int o2, int hasF, int do_sm, int mode, int widx,
    float* __restrict__ accb, float* __restrict__ out,
    const ushort* __restrict__ gWT, const float* __restrict__ dinv_d,
    const float* __restrict__ dinv_q, ushort* __restrict__ htmp) {
  __shared__ float s_ld[16 * LD_STRIDE];
  __shared__ float s_lq[16 * 16];
  __shared__ float s_red[16 * 8];
  int tid = threadIdx.x;
  int wave = tid >> 6, lane = tid & 63;
  int col = lane & 15, quad = lane >> 4;

  if (blockIdx.x >= 128) {
    int gblk = blockIdx.x - 128;
    bool isQ = gblk >= 256;
    int node0;
    if (isQ) node0 = (gblk - 256) * 128;
    else node0 = swz_g(gblk) * 512 + (gblk >> 6) * 128;
    int mloc = node0 + wave * 16;
    const ushort* X = isQ ? qbf : dbf;
    const float* dv = isQ ? dinv_q : dinv_d;
    size_t hbase = isQ ? (size_t)cNd : 0;
    floatx4 acc[8];
#pragma unroll
    for (int ct = 0; ct < 8; ++ct)
#pragma unroll
      for (int r = 0; r < 4; ++r) acc[ct][r] = 0.0f;
#pragma unroll
    for (int kc = 0; kc < 4; ++kc) {
      bf16x8 a = *(const bf16x8*)(X + (size_t)(mloc + col) * 128 + kc * 32 + quad * 8);
#pragma unroll
      for (int ct = 0; ct < 8; ++ct) {
        bf16x8 b = *(const bf16x8*)(gWT + (size_t)(ct * 16 + col) * 128 + kc * 32 + quad * 8);
        acc[ct] = __builtin_amdgcn_mfma_f32_16x16x32_bf16(a, b, acc[ct], 0, 0, 0);
      }
    }
    float sc[4];
#pragma unroll
    for (int r = 0; r < 4; ++r) sc[r] = dv[mloc + quad * 4 + r];
#pragma unroll
    for (int ct = 0; ct < 8; ++ct)
#pragma unroll
      for (int r = 0; r < 4; ++r)
        htmp[(hbase + mloc + quad * 4 + r) * 128 + ct * 16 + col] = f2bf(acc[ct][r] * sc[r]);
    return;
  }

  int b = swz_g(blockIdx.x & 63);
  int qh = blockIdx.x >> 6;
  int n0 = wave * 64;

  bf16x8 bfr[4][4];
#pragma unroll
  for (int s = 0; s < 4; ++s)
#pragma unroll
    for (int kc = 0; kc < 4; ++kc)
      bfr[s][kc] = *(const bf16x8*)(dbf + ((size_t)(b * 512 + n0 + s * 16 + col) << 7) +
                                    kc * 32 + quad * 8);
  bf16x8 aq[4];
#pragma unroll
  for (int kc = 0; kc < 4; ++kc)
    aq[kc] = *(const bf16x8*)(qbf + (size_t)(b * 32 + qh * 16 + col) * 128 +
                              kc * 32 + quad * 8);

  floatx4 att[4];
#pragma unroll
  for (int s = 0; s < 4; ++s)
#pragma unroll
    for (int r = 0; r < 4; ++r) att[s][r] = 0.0f;
#pragma unroll
  for (int kc = 0; kc < 4; ++kc)
#pragma unroll
    for (int s = 0; s < 4; ++s)
      att[s] = __builtin_amdgcn_mfma_f32_16x16x32_bf16(aq[kc], bfr[s][kc], att[s], 0, 0, 0);
  const float sc = 0.088388347648318440550f;
#pragma unroll
  for (int s = 0; s < 4; ++s)
#pragma unroll
    for (int r = 0; r < 4; ++r) att[s][r] *= sc;

  {
    bf16x8 vn2[4];
#pragma unroll
    for (int kc = 0; kc < 4; ++kc)
      vn2[kc] = *(const bf16x8*)(vnbf + col * 256 + 128 + kc * 32 + quad * 8);
#pragma unroll
    for (int s = 0; s < 4; ++s) {
      floatx4 lda;
#pragma unroll
      for (int r = 0; r < 4; ++r) lda[r] = 0.0f;
#pragma unroll
      for (int kc = 0; kc < 4; ++kc)
        lda = __builtin_amdgcn_mfma_f32_16x16x32_bf16(bfr[s][kc], vn2[kc], lda, 0, 0, 0);
#pragma unroll
      for (int r = 0; r < 4; ++r)
        s_ld[col * LD_STRIDE + n0 + s * 16 + quad * 4 + r] = lda[r];
    }
  }
  if (wave == 0) {
    bf16x8 vn1[4];
#pragma unroll
    for (int kc = 0; kc < 4; ++kc)
      vn1[kc] = *(const bf16x8*)(vnbf + col * 256 + kc * 32 + quad * 8);
    floatx4 lqa;
#pragma unroll
    for (int r = 0; r < 4; ++r) lqa[r] = 0.0f;
#pragma unroll
    for (int kc = 0; kc < 4; ++kc)
      lqa = __builtin_amdgcn_mfma_f32_16x16x32_bf16(aq[kc], vn1[kc], lqa, 0, 0, 0);
#pragma unroll
    for (int r = 0; r < 4; ++r) s_lq[col * 16 + quad * 4 + r] = lqa[r];
  }
  __syncthreads();

  float red[4], M[4];
#pragma unroll
  for (int r = 0; r < 4; ++r) {
    float m = fmaxf(fmaxf(att[0][r], att[1][r]), fmaxf(att[2][r], att[3][r]));
#pragma unroll
    for (int o = 1; o < 16; o <<= 1) m = fmaxf(m, __shfl_xor(m, o, 64));
    red[r] = m;
  }
  if (col == 0)
#pragma unroll
    for (int r = 0; r < 4; ++r) s_red[(quad * 4 + r) * 8 + wave] = red[r];
  __syncthreads();
#pragma unroll
  for (int r = 0; r < 4; ++r) {
    float m = s_red[(quad * 4 + r) * 8];
#pragma unroll
    for (int w = 1; w < 8; ++w) m = fmaxf(m, s_red[(quad * 4 + r) * 8 + w]);
    M[r] = m;
  }
  __syncthreads();
#pragma unroll
  for (int s = 0; s < 4; ++s)
#pragma unroll
    for (int r = 0; r < 4; ++r) att[s][r] = fexp(att[s][r] - M[r]);
#pragma unroll
  for (int r = 0; r < 4; ++r) {
    float m = att[0][r] + att[1][r] + att[2][r] + att[3][r];
#pragma unroll
    for (int o = 1; o < 16; o <<= 1) m += __shfl_xor(m, o, 64);
    red[r] = m;
  }
  if (col == 0)
#pragma unroll
    for (int r = 0; r < 4; ++r) s_red[(quad * 4 + r) * 8 + wave] = red[r];
  __syncthreads();
#pragma unroll
  for (int r = 0; r < 4; ++r) {
    float m = s_red[(quad * 4 + r) * 8];
#pragma unroll
    for (int w = 1; w < 8; ++w) m += s_red[(quad * 4 + r) * 8 + w];
    M[r] = frcp(m);
  }
  __syncthreads();
#pragma unroll
  for (int s = 0; s < 4; ++s)
#pragma unroll
    for (int r = 0; r < 4; ++r) att[s][r] *= M[r];

  floatx4 eacc[4], facc[4];
#pragma unroll
  for (int s = 0; s < 4; ++s)
#pragma unroll
    for (int r = 0; r < 4; ++r) { eacc[s][r] = 0.0f; facc[s][r] = 0.0f; }

#pragma unroll 4
  for (int k = 0; k < 16; ++k) {
    const ushort* qk = qw + ((size_t)(b * 16 + k) << 12) + (qh * 16 + col) * 128 + quad * 8;
    bf16x8 a0 = *(const bf16x8*)(qk);
    bf16x8 a1 = *(const bf16x8*)(qk + 32);
    bf16x8 a2 = *(const bf16x8*)(qk + 64);
    bf16x8 a3 = *(const bf16x8*)(qk + 96);
    floatx4 bil[4];
#pragma unroll
    for (int s = 0; s < 4; ++s) {
#pragma unroll
      for (int r = 0; r < 4; ++r) bil[s][r] = 0.0f;
      bil[s] = __builtin_amdgcn_mfma_f32_16x16x32_bf16(a0, bfr[s][0], bil[s], 0, 0, 0);
      bil[s] = __builtin_amdgcn_mfma_f32_16x16x32_bf16(a1, bfr[s][1], bil[s], 0, 0, 0);
      bil[s] = __builtin_amdgcn_mfma_f32_16x16x32_bf16(a2, bfr[s][2], bil[s], 0, 0, 0);
      bil[s] = __builtin_amdgcn_mfma_f32_16x16x32_bf16(a3, bfr[s][3], bil[s], 0, 0, 0);
    }
    float bnk = bn[k], cwk = cw[k];
    float wkk = 0.0f;
    if (hasF) {
      wkk = w_end[o1 + k];
      if (o2 >= 0) wkk += w_end[o2 + k];
    }
    float lqv[4];
#pragma unroll
    for (int r = 0; r < 4; ++r) lqv[r] = s_lq[k * 16 + quad * 4 + r] + bnk;
#pragma unroll
    for (int s = 0; s < 4; ++s) {
      float ldv = s_ld[k * LD_STRIDE + n0 + s * 16 + col];
#pragma unroll
      for (int r = 0; r < 4; ++r) {
        float sg = fsigmoid(bil[s][r] + lqv[r] + ldv);
        eacc[s][r] += cwk * sg;
        facc[s][r] += wkk * sg;
      }
    }
  }

#pragma unroll
  for (int s = 0; s < 4; ++s)
#pragma unroll
    for (int r = 0; r < 4; ++r) {
      eacc[s][r] *= att[s][r];
      facc[s][r] *= att[s][r];
    }
  if (do_sm) {
#pragma unroll
    for (int r = 0; r < 4; ++r) {
      float m = fmaxf(fmaxf(eacc[0][r], eacc[1][r]), fmaxf(eacc[2][r], eacc[3][r]));
#pragma unroll
      for (int o = 1; o < 16; o <<= 1) m = fmaxf(m, __shfl_xor(m, o, 64));
      red[r] = m;
    }
    if (col == 0)
#pragma unroll
      for (int r = 0; r < 4; ++r) s_red[(quad * 4 + r) * 8 + wave] = red[r];
    __syncthreads();
#pragma unroll
    for (int r = 0; r < 4; ++r) {
      float m = s_red[(quad * 4 + r) * 8];
#pragma unroll
      for (int w = 1; w < 8; ++w) m = fmaxf(m, s_red[(quad * 4 + r) * 8 + w]);
      M[r] = m;
    }
    __syncthreads();
#pragma unroll
    for (int s = 0; s < 4; ++s)
#pragma unroll
      for (int r = 0; r < 4; ++r) eacc[s][r] = fexp(eacc[s][r] - M[r]);
#pragma unroll
    for (int r = 0; r < 4; ++r) {
      float m = eacc[0][r] + eacc[1][r] + eacc[2][r] + eacc[3][r];
#pragma unroll
      for (int o = 1; o < 16; o <<= 1) m += __shfl_xor(m, o, 64);
      red[r] = m;
    }
    if (col == 0)
#pragma unroll
      for (int r = 0; r < 4; ++r) s_red[(quad * 4 + r) * 8 + wave] = red[r];
    __syncthreads();
#pragma unroll
    for (int r = 0; r < 4; ++r) {
      float m = s_red[(quad * 4 + r) * 8];
#pragma unroll
      for (int w = 1; w < 8; ++w) m += s_red[(quad * 4 + r) * 8 + w];
      M[r] = frcp(m);
    }
    __syncthreads();
#pragma unroll
    for (int s = 0; s < 4; ++s)
#pragma unroll
      for (int r = 0; r < 4; ++r) eacc[s][r] *= M[r];
  }
  float w = w_end[widx];
#pragma unroll
  for (int s = 0; s < 4; ++s)
#pragma unroll
    for (int r = 0; r < 4; ++r) eacc[s][r] = w * eacc[s][r] + (hasF ? facc[s][r] : 0.0f);

  if (mode == 0) {
#pragma unroll
    for (int s = 0; s < 4; ++s)
#pragma unroll
      for (int r = 0; r < 4; ++r)
        accb[((size_t)(b * 32 + qh * 16 + quad * 4 + r) << 9) + n0 + s * 16 + col] =
            eacc[s][r];
  } else if (mode == 1) {
#pragma unroll
    for (int s = 0; s < 4; ++s)
#pragma unroll
      for (int r = 0; r < 4; ++r)
        accb[((size_t)(b * 32 + qh * 16 + quad * 4 + r) << 9) + n0 + s * 16 + col] +=
            eacc[s][r];
  } else {
    float be = b_end[0];
#pragma unroll
    for (int s = 0; s < 4; ++s)
#pragma unroll
      for (int r = 0; r < 4; ++r)
        eacc[s][r] += accb[((size_t)(b * 32 + qh * 16 + quad * 4 + r) << 9) +
                           n0 + s * 16 + col] + be;
#pragma unroll
    for (int r = 0; r < 4; ++r) {
      float m = fmaxf(fmaxf(eacc[0][r], eacc[1][r]), fmaxf(eacc[2][r], eacc[3][r]));
#pragma unroll
      for (int o = 1; o < 16; o <<= 1) m = fmaxf(m, __shfl_xor(m, o, 64));
      red[r] = m;
    }
    if (col == 0)
#pragma unroll
      for (int r = 0; r < 4; ++r) s_red[(quad * 4 + r) * 8 + wave] = red[r];
    __syncthreads();
#pragma unroll
    for (int r = 0; r < 4; ++r) {
      float m = s_red[(quad * 4 + r) * 8];
#pragma unroll
      for (int w2 = 1; w2 < 8; ++w2) m = fmaxf(m, s_red[(quad * 4 + r) * 8 + w2]);
      M[r] = m;
    }
    __syncthreads();
#pragma unroll
    for (int s = 0; s < 4; ++s)
#pragma unroll
      for (int r = 0; r < 4; ++r) eacc[s][r] = fexp(eacc[s][r] - M[r]);
#pragma unroll
    for (int r = 0; r < 4; ++r) {
      float m = eacc[0][r] + eacc[1][r] + eacc[2][r] + eacc[3][r];
#pragma unroll
      for (int o = 1; o < 16; o <<= 1) m += __shfl_xor(m, o, 64);
      red[r] = m;
    }
    if (col == 0)
#pragma unroll
      for (int r = 0; r < 4; ++r) s_red[(quad * 4 + r) * 8 + wave] = red[r];
    __syncthreads();
#pragma unroll
    for (int r = 0; r < 4; ++r) {
      float m = s_red[(quad * 4 + r) * 8];
#pragma unroll
      for (int w2 = 1; w2 < 8; ++w2) m += s_red[(quad * 4 + r) * 8 + w2];
      M[r] = frcp(m);
    }
#pragma unroll
    for (int s = 0; s < 4; ++s)
#pragma unroll
      for (int r = 0; r < 4; ++r)
        out[((size_t)(b * 32 + qh * 16 + quad * 4 + r) << 9) + n0 + s * 16 + col] =
            eacc[s][r] * M[r];
  }
}

// ---------------------------------------------------------------------------
// Host orchestration: cooperative mega-kernel (1 dispatch) with R0 fallback.
// ---------------------------------------------------------------------------
extern "C" void kernel_launch(void* const* d_in, const int* in_sizes, int n_in,
                              void* d_out, int out_size, void* d_ws, size_t ws_size,
                              hipStream_t stream) {
  (void)in_sizes; (void)n_in; (void)out_size; (void)ws_size;
  const float* x_d = (const float*)d_in[0];
  const float* x_q = (const float*)d_in[1];
  const int* ei_d = (const int*)d_in[2];
  const int* ei_q = (const int*)d_in[3];
  const float* W1 = (const float*)d_in[6];
  const float* b1 = (const float*)d_in[7];
  const float* W2 = (const float*)d_in[8];
  const float* b2 = (const float*)d_in[9];
  const float* W3 = (const float*)d_in[10];
  const float* b3 = (const float*)d_in[11];
  const float* Wn[3] = {(const float*)d_in[12], (const float*)d_in[17], (const float*)d_in[22]};
  const float* Vn[3] = {(const float*)d_in[13], (const float*)d_in[18], (const float*)d_in[23]};
  const float* bn[3] = {(const float*)d_in[14], (const float*)d_in[19], (const float*)d_in[24]};
  const float* cw[3] = {(const float*)d_in[15], (const float*)d_in[20], (const float*)d_in[25]};
  const float* w_end = (const float*)d_in[27];
  const float* b_end = (const float*)d_in[28];
  float* out = (float*)d_out;

  char* wsp = (char*)d_ws;
  auto alloc = [&](size_t nbytes) {
    void* p = (void*)wsp;
    wsp += (nbytes + 255) & ~(size_t)255;
    return p;
  };
  int* cnt_d = (int*)alloc(cNd * 4);
  int* cnt_q = (int*)alloc(cNq * 4);
  int* cur_d = (int*)alloc(cNd * 4);
  int* cur_q = (int*)alloc(cNq * 4);
  float* dinv_d = (float*)alloc(cNd * 4);
  float* dinv_q = (float*)alloc(cNq * 4);
  int* rp_d = (int*)alloc(cNd * 4);
  int* rp_q = (int*)alloc(cNq * 4);
  int* col_d = (int*)alloc((size_t)cEd * 4);
  int* col_q = (int*)alloc((size_t)cEq * 4);
  ushort* xdbf = (ushort*)alloc((size_t)cNd * 64 * 2);
  ushort* xqbf = (ushort*)alloc((size_t)cNq * 64 * 2);
  ushort* w1T = (ushort*)alloc(128 * 64 * 2);
  ushort* w2T = (ushort*)alloc(128 * 128 * 2);
  ushort* w3T = (ushort*)alloc(128 * 128 * 2);
  ushort* wnT[3];
  for (int l = 0; l < 3; ++l) wnT[l] = (ushort*)alloc((size_t)16 * 128 * 128 * 2);
  ushort* vnbf[3];
  for (int l = 0; l < 3; ++l) vnbf[l] = (ushort*)alloc(16 * 256 * 2);
  ushort* htmp = (ushort*)alloc((size_t)(cNd + cNq) * 128 * 2);
  ushort* dbf = (ushort*)alloc((size_t)cNd * 128 * 2);
  ushort* qbf[3];
  for (int l = 0; l < 3; ++l) qbf[l] = (ushort*)alloc((size_t)cNq * 128 * 2);
  float* accb = (float*)alloc((size_t)cB * cNQ * cND * 4);
  ushort* qwbuf = (ushort*)alloc((size_t)cB * 16 * 32 * 128 * 2);

  const int* src_d = ei_d;
  const int* dst_d = ei_d + cEd;
  const int* src_q = ei_q;
  const int* dst_q = ei_q + cEq;

  MP P;
  P.x_d = x_d; P.x_q = x_q;
  P.src_d = src_d; P.dst_d = dst_d; P.src_q = src_q; P.dst_q = dst_q;
  P.W1 = W1; P.W2 = W2; P.W3 = W3;
  P.Wn0 = Wn[0]; P.Wn1 = Wn[1]; P.Wn2 = Wn[2];
  P.V0 = Vn[0]; P.V1 = Vn[1]; P.V2 = Vn[2];
  P.b1 = b1; P.b2 = b2; P.b3 = b3;
  P.bn0 = bn[0]; P.bn1 = bn[1]; P.bn2 = bn[2];
  P.cw0 = cw[0]; P.cw1 = cw[1]; P.cw2 = cw[2];
  P.w_end = w_end; P.b_end = b_end;
  P.xdbf = xdbf; P.xqbf = xqbf;
  P.w1T = w1T; P.w2T = w2T; P.w3T = w3T;
  P.wnT0 = wnT[0]; P.wnT1 = wnT[1]; P.wnT2 = wnT[2];
  P.vnbf0 = vnbf[0]; P.vnbf1 = vnbf[1]; P.vnbf2 = vnbf[2];
  P.cnt_d = cnt_d; P.cnt_q = cnt_q; P.rp_d = rp_d; P.rp_q = rp_q;
  P.dinv_d = dinv_d; P.dinv_q = dinv_q;
  P.col_d = col_d; P.col_q = col_q;
  P.htmp = htmp; P.dbf = dbf;
  P.qbf0 = qbf[0]; P.qbf1 = qbf[1]; P.qbf2 = qbf[2];
  P.qwbuf = qwbuf; P.accb = accb; P.out = out;

  void* kargs[] = {(void*)&P};
  hipError_t err = hipLaunchCooperativeKernel((const void*)k_mega, dim3(NB), dim3(NT),
                                              kargs, 0, stream);
  if (err == hipSuccess) return;
  (void)hipGetLastError();  // clear sticky error, fall back to R0 pipeline

  hipMemsetAsync(cnt_d, 0, (size_t)2 * (cNd + cNq) * 4, stream);
  k_front<<<NB_CVT + NB_T2BF + NB_CNT, 256, 0, stream>>>(
      x_d, x_q, Vn[0], Vn[1], Vn[2], xdbf, xqbf, vnbf[0], vnbf[1], vnbf[2], W1, W2,
      W3, Wn[0], Wn[1], Wn[2], w1T, w2T, w3T, wnT[0], wnT[1], wnT[2], dst_d, dst_q,
      cnt_d, cnt_q);
  k_scan_dinv<<<136, 512, 0, stream>>>(cnt_d, cnt_q, rp_d, rp_q, dinv_d, dinv_q);
  k_fill_gemm1<<<NB_FILL + 544, 256, 0, stream>>>(
      src_d, dst_d, src_q, dst_q, rp_d, rp_q, cur_d, cur_q, col_d, col_q, xdbf, xqbf,
      w1T, dinv_d, dinv_q, htmp);

  const float* bias[3] = {b1, b2, b3};
  const ushort* nextWT[3] = {w2T, w3T, nullptr};
  const int o1s[3] = {0, 19, 3};
  const int o2s[3] = {-1, -1, 35};
  const int hasF[3] = {0, 1, 1};
  const int dosms[3] = {1, 0, 1};
  const int modes[3] = {0, 1, 2};
  for (int l = 0; l < 3; ++l) {
    gmn_gather_merged<<<(cNd + cNq) / 8, 256, 0, stream>>>(
        htmp, rp_d, cnt_d, col_d, dinv_d, rp_q, cnt_q, col_q, dinv_q, bias[l], dbf,
        qbf[l]);
    gmn_qw<<<1024, 256, 0, stream>>>(qbf[l], wnT[l], qwbuf);
    int grid = (l < 2) ? (128 + 272) : 128;
    k_level_gemm<<<grid, 512, 0, stream>>>(
        qbf[l], dbf, qwbuf, vnbf[l], bn[l], cw[l], w_end, b_end, o1s[l], o2s[l],
        hasF[l], dosms[l], modes[l], l, accb, out, nextWT[l], dinv_d, dinv_q, htmp);
  }
}

// Round 4
// 311.413 us; speedup vs baseline: 2.2045x; 2.2045x over previous
//
#include <hip/hip_runtime.h>
#include <math.h>

// ---------------------------------------------------------------------------
// Problem constants (fixed production sizes from the reference)
// ---------------------------------------------------------------------------
namespace {
constexpr int cB  = 64;
constexpr int cNQ = 32;
constexpr int cND = 512;
constexpr int cNd = cB * cND;   // 32768
constexpr int cNq = cB * cNQ;   // 2048
constexpr int cEd = cNd * 8;    // 262144 (exactly 4096 per graph, graph-sorted)
constexpr int cEq = cNq * 8;    // 16384  (exactly 256 per graph, graph-sorted)
constexpr int LD_STRIDE = 516;
// front kernel block ranges: CSR first (starts immediately), then cvt/transpose
constexpr int NB_CSRD = 64;                    // [0,64)
constexpr int NB_CSRQ = 8;                     // [64,72)
constexpr int CVT0 = NB_CSRD + NB_CSRQ;        // 72
constexpr int NB_CVT = 2188;                   // [72,2260)
constexpr int TR0 = CVT0 + NB_CVT;             // 2260
constexpr int NB_T2BF = 808;                   // [2260,3068)
}

#define F4C(p) (*(const float4*)(p))

typedef __attribute__((ext_vector_type(8))) __bf16 bf16x8;
typedef __attribute__((ext_vector_type(4))) float floatx4;

__device__ __forceinline__ ushort f2bf(float f) {
  union { float f; unsigned u; } v;
  v.f = f;
  unsigned u = v.u;
  return (ushort)((u + 0x7fffu + ((u >> 16) & 1u)) >> 16);
}
__device__ __forceinline__ float bf2f(ushort u) {
  union { unsigned u; float f; } v;
  v.u = ((unsigned)u) << 16;
  return v.f;
}
__device__ __forceinline__ float4 us4f4(ushort4 u) {
  return make_float4(bf2f(u.x), bf2f(u.y), bf2f(u.z), bf2f(u.w));
}
__device__ __forceinline__ ushort4 f4us4(float4 f) {
  ushort4 o;
  o.x = f2bf(f.x); o.y = f2bf(f.y); o.z = f2bf(f.z); o.w = f2bf(f.w);
  return o;
}
__device__ __forceinline__ float fexp2(float x) {
#if __has_builtin(__builtin_amdgcn_exp2f)
  return __builtin_amdgcn_exp2f(x);
#else
  return exp2f(x);
#endif
}
__device__ __forceinline__ float frcp(float x) {
#if __has_builtin(__builtin_amdgcn_rcpf)
  return __builtin_amdgcn_rcpf(x);
#else
  return 1.0f / x;
#endif
}
__device__ __forceinline__ float fsigmoid(float z) {
  return frcp(1.0f + fexp2(z * -1.4426950408889634f));
}
__device__ __forceinline__ float fexp(float x) { return fexp2(x * 1.4426950408889634f); }

// XCD-affinity swizzle (low 6 bits only)
__device__ __forceinline__ int swz_g(int j) { return (((j >> 3) & 7) << 3) | (j & 7); }

// ---------------------------------------------------------------------------
// D1: per-graph CSR build (blocks FIRST so they start immediately) +
// conversions + weight transposes. grid 3068 x 256.
// ---------------------------------------------------------------------------
__global__ __launch_bounds__(256) void k_front_csr(
    const float* __restrict__ xd, const float* __restrict__ xq,
    const float* __restrict__ v0, const float* __restrict__ v1,
    const float* __restrict__ v2, ushort* __restrict__ oxd, ushort* __restrict__ oxq,
    ushort* __restrict__ ov0, ushort* __restrict__ ov1, ushort* __restrict__ ov2,
    const float* __restrict__ W1, const float* __restrict__ W2,
    const float* __restrict__ W3, const float* __restrict__ Wn0,
    const float* __restrict__ Wn1, const float* __restrict__ Wn2,
    ushort* __restrict__ o1, ushort* __restrict__ o2, ushort* __restrict__ o3,
    ushort* __restrict__ on0, ushort* __restrict__ on1, ushort* __restrict__ on2,
    const int* __restrict__ src_d, const int* __restrict__ dst_d,
    const int* __restrict__ src_q, const int* __restrict__ dst_q,
    int* __restrict__ cnt_d, int* __restrict__ cnt_q,
    int* __restrict__ rp_d, int* __restrict__ rp_q,
    float* __restrict__ dinv_d, float* __restrict__ dinv_q,
    int* __restrict__ col_d, int* __restrict__ col_q) {
  __shared__ float tile[32][33];
  __shared__ int s_cnt[512];
  __shared__ int s_base[512];
  __shared__ int s_cur[512];
  int blk = blockIdx.x, tid = threadIdx.x;
  if (blk < NB_CSRD) {
    // ---------------- per-graph data CSR build (512 nodes, 4096 edges) ------
    int g = blk;
    const int* dstg = dst_d + g * 4096;
    const int* srcg = src_d + g * 4096;
    int nbase = g * 512;
    s_cnt[tid] = 0; s_cnt[tid + 256] = 0;
    __syncthreads();
    for (int e = tid; e < 4096; e += 256) atomicAdd(&s_cnt[dstg[e] - nbase], 1);
    __syncthreads();
    int c0 = s_cnt[tid], c1 = s_cnt[tid + 256];
    s_base[tid] = c0; s_base[tid + 256] = c1;
    __syncthreads();
    // Hillis-Steele inclusive scan over 512 entries with 256 threads
    for (int off = 1; off < 512; off <<= 1) {
      int a = (tid >= off) ? s_base[tid - off] : 0;
      int b = (tid + 256 >= off) ? s_base[tid + 256 - off] : 0;
      __syncthreads();
      s_base[tid] += a; s_base[tid + 256] += b;
      __syncthreads();
    }
    int e0 = s_base[tid] - c0, e1 = s_base[tid + 256] - c1;  // exclusive
    s_base[tid] = e0; s_base[tid + 256] = e1;
    s_cur[tid] = 0; s_cur[tid + 256] = 0;
    cnt_d[nbase + tid] = c0;
    cnt_d[nbase + tid + 256] = c1;
    rp_d[nbase + tid] = g * 4096 + e0;
    rp_d[nbase + tid + 256] = g * 4096 + e1;
    dinv_d[nbase + tid] = 1.0f / sqrtf((float)(c0 + 1));
    dinv_d[nbase + tid + 256] = 1.0f / sqrtf((float)(c1 + 1));
    __syncthreads();
    for (int e = tid; e < 4096; e += 256) {
      int d = dstg[e] - nbase;
      int p = atomicAdd(&s_cur[d], 1);
      col_d[g * 4096 + s_base[d] + p] = srcg[e];
    }
  } else if (blk < CVT0) {
    // ---------------- per-graph query CSR build (8 graphs/block) ------------
    int qb = blk - NB_CSRD;
    int lg = tid >> 5, lane32 = tid & 31;
    int g = qb * 8 + lg;
    const int* dstg = dst_q + g * 256;
    const int* srcg = src_q + g * 256;
    int nbase = g * 32;
    s_cnt[tid] = 0;
    __syncthreads();
#pragma unroll
    for (int j = 0; j < 8; ++j)
      atomicAdd(&s_cnt[lg * 32 + (dstg[lane32 + j * 32] - nbase)], 1);
    __syncthreads();
    int v = s_cnt[tid];
    int incl = v;
#pragma unroll
    for (int off = 1; off < 32; off <<= 1) {
      int t = __shfl_up(incl, off, 32);
      if (lane32 >= off) incl += t;
    }
    int excl = incl - v;
    cnt_q[nbase + lane32] = v;
    rp_q[nbase + lane32] = g * 256 + excl;
    dinv_q[nbase + lane32] = 1.0f / sqrtf((float)(v + 1));
    s_base[tid] = excl;
    s_cur[tid] = 0;
    __syncthreads();
#pragma unroll
    for (int j = 0; j < 8; ++j) {
      int e = lane32 + j * 32;
      int d = dstg[e] - nbase;
      int p = atomicAdd(&s_cur[lg * 32 + d], 1);
      col_q[g * 256 + s_base[lg * 32 + d] + p] = srcg[e];
    }
  } else if (blk < TR0) {
    int b2 = blk - CVT0;
    const float* src;
    ushort* dst;
    int i;
    if (b2 < 2048) { src = xd; dst = oxd; i = b2 * 256 + tid; }
    else if (b2 < 2176) { src = xq; dst = oxq; i = (b2 - 2048) * 256 + tid; }
    else if (b2 < 2180) { src = v0; dst = ov0; i = (b2 - 2176) * 256 + tid; }
    else if (b2 < 2184) { src = v1; dst = ov1; i = (b2 - 2180) * 256 + tid; }
    else { src = v2; dst = ov2; i = (b2 - 2184) * 256 + tid; }
    *(ushort4*)(dst + (size_t)i * 4) = f4us4(F4C(src + (size_t)i * 4));
  } else {
    int b5 = blk - TR0;
    const float* in;
    ushort* out;
    int R, C, bt, t;
    if (b5 < 8)        { in = W1;  out = o1;  R = 64;  C = 128; bt = 0; t = b5; }
    else if (b5 < 24)  { in = W2;  out = o2;  R = 128; C = 128; bt = 0; t = b5 - 8; }
    else if (b5 < 40)  { in = W3;  out = o3;  R = 128; C = 128; bt = 0; t = b5 - 24; }
    else if (b5 < 296) { in = Wn0; out = on0; R = 128; C = 128; bt = (b5 - 40) >> 4;  t = (b5 - 40) & 15; }
    else if (b5 < 552) { in = Wn1; out = on1; R = 128; C = 128; bt = (b5 - 296) >> 4; t = (b5 - 296) & 15; }
    else               { in = Wn2; out = on2; R = 128; C = 128; bt = (b5 - 552) >> 4; t = (b5 - 552) & 15; }
    int tilesC = C >> 5;
    int tr = t / tilesC, tc = t - tr * tilesC;
    int tx = tid & 31, ty = tid >> 5;
    const float* ib = in + (size_t)bt * R * C;
    ushort* ob = out + (size_t)bt * R * C;
#pragma unroll
    for (int i = 0; i < 4; ++i)
      tile[ty + i * 8][tx] = ib[(tr * 32 + ty + i * 8) * C + tc * 32 + tx];
    __syncthreads();
#pragma unroll
    for (int i = 0; i < 4; ++i)
      ob[(size_t)(tc * 32 + ty + i * 8) * R + tr * 32 + tx] = f2bf(tile[tx][ty + i * 8]);
  }
}

// ---------------------------------------------------------------------------
// D2: GCN GEMM layer 1 (KD=64). grid 544 x 256.
// ---------------------------------------------------------------------------
__global__ __launch_bounds__(256) void k_gemm1(
    const ushort* __restrict__ xdbf, const ushort* __restrict__ xqbf,
    const ushort* __restrict__ w1T, const float* __restrict__ dinv_d,
    const float* __restrict__ dinv_q, ushort* __restrict__ htmp) {
  int blk2 = blockIdx.x, tid = threadIdx.x;  // data [0,512) swizzled, query [512,544)
  int wave = tid >> 6, lane = tid & 63;
  int col = lane & 15, quad = lane >> 4;
  bool isQ = blk2 >= 512;
  int node0;
  if (isQ) node0 = (blk2 - 512) * 64;
  else node0 = swz_g(blk2) * 512 + (blk2 >> 6) * 64;
  int mloc = node0 + wave * 16;
  const ushort* X = isQ ? xqbf : xdbf;
  const float* dv = isQ ? dinv_q : dinv_d;
  size_t hbase = isQ ? (size_t)cNd : 0;
  floatx4 acc[8];
#pragma unroll
  for (int ct = 0; ct < 8; ++ct)
#pragma unroll
    for (int r = 0; r < 4; ++r) acc[ct][r] = 0.0f;
#pragma unroll
  for (int kc = 0; kc < 2; ++kc) {
    bf16x8 a = *(const bf16x8*)(X + (size_t)(mloc + col) * 64 + kc * 32 + quad * 8);
#pragma unroll
    for (int ct = 0; ct < 8; ++ct) {
      bf16x8 b = *(const bf16x8*)(w1T + (size_t)(ct * 16 + col) * 64 + kc * 32 + quad * 8);
      acc[ct] = __builtin_amdgcn_mfma_f32_16x16x32_bf16(a, b, acc[ct], 0, 0, 0);
    }
  }
  float sc[4];
#pragma unroll
  for (int r = 0; r < 4; ++r) sc[r] = dv[mloc + quad * 4 + r];
#pragma unroll
  for (int ct = 0; ct < 8; ++ct)
#pragma unroll
    for (int r = 0; r < 4; ++r)
      htmp[(hbase + mloc + quad * 4 + r) * 128 + ct * 16 + col] = f2bf(acc[ct][r] * sc[r]);
}

// ---------------------------------------------------------------------------
// GCN aggregate (byte-identical to R0's verified gmn_gather_merged).
// grid 4352 x 256.
// ---------------------------------------------------------------------------
__global__ __launch_bounds__(256) void gmn_gather_merged(
    const ushort* __restrict__ htmp, const int* __restrict__ rp_d,
    const int* __restrict__ cnt_d, const int* __restrict__ col_d,
    const float* __restrict__ dinv_d, const int* __restrict__ rp_q,
    const int* __restrict__ cnt_q, const int* __restrict__ col_q,
    const float* __restrict__ dinv_q, const float* __restrict__ bias,
    ushort* __restrict__ dbf, ushort* __restrict__ qbf) {
  int blk = blockIdx.x, tid = threadIdx.x;
  bool isQ = blk >= 4096;
  int node;
  if (isQ) {
    int j = blk - 4096;
    node = swz_g(j) * 32 + (j >> 6) * 8 + (tid >> 5);
  } else {
    node = swz_g(blk) * 512 + (blk >> 6) * 8 + (tid >> 5);
  }
  int l = tid & 31;
  const ushort* hs = htmp + (isQ ? (size_t)cNd * 128 : 0);
  const int* rp = isQ ? rp_q : rp_d;
  const int* cnt = isQ ? cnt_q : cnt_d;
  const int* col = isQ ? col_q : col_d;
  const float* dinv = isQ ? dinv_q : dinv_d;
  ushort* outp = isQ ? qbf : dbf;
  int c = cnt[node], s0 = rp[node];
  float dt = dinv[node];
  float4 acc = us4f4(*(const ushort4*)(hs + (size_t)node * 128 + l * 4));
  int cm = c < 32 ? c : 32;
  for (int j0 = 0; j0 < cm; j0 += 8) {
    int ss[8];
    ushort4 v[8];
#pragma unroll
    for (int t = 0; t < 8; ++t) {
      int jj = j0 + t;
      ss[t] = (jj < cm) ? col[s0 + jj] : -1;
    }
#pragma unroll
    for (int t = 0; t < 8; ++t)
      if (ss[t] >= 0) v[t] = *(const ushort4*)(hs + (size_t)ss[t] * 128 + l * 4);
#pragma unroll
    for (int t = 0; t < 8; ++t) {
      if (ss[t] >= 0) {
        float4 f = us4f4(v[t]);
        acc.x += f.x; acc.y += f.y; acc.z += f.z; acc.w += f.w;
      }
    }
  }
  for (int j = 32; j < c; ++j) {
    int s = col[s0 + j];
    float4 f = us4f4(*(const ushort4*)(hs + (size_t)s * 128 + l * 4));
    acc.x += f.x; acc.y += f.y; acc.z += f.z; acc.w += f.w;
  }
  float4 bv = F4C(bias + l * 4);
  float4 r;
  r.x = fmaxf(acc.x * dt + bv.x, 0.0f);
  r.y = fmaxf(acc.y * dt + bv.y, 0.0f);
  r.z = fmaxf(acc.z * dt + bv.z, 0.0f);
  r.w = fmaxf(acc.w * dt + bv.w, 0.0f);
  *(ushort4*)(outp + (size_t)node * 128 + l * 4) = f4us4(r);
}

// ---------------------------------------------------------------------------
// Merged dispatch: fused NTN level WITH in-block qW [blk<128, 512 thr] +
// next-layer GCN GEMM KD=128 [blk in [128,128+272)].
// qW is computed per 4-k chunk by the 8 waves (wave = (k, e-half); same MFMA
// and bf16 rounding as the old gmn_qw), staged in XOR-swizzled LDS, then the
// bil loop reads its A-fragments from LDS. Removes the qw dispatch + qwbuf.
// ---------------------------------------------------------------------------
__global__ __launch_bounds__(512, 1) void k_level_gemm(
    const ushort* __restrict__ qbf, const ushort* __restrict__ dbf,
    const ushort* __restrict__ wnT, const ushort* __restrict__ vnbf,
    const float* __restrict__ bn, const float* __restrict__ cw,
    const float* __restrict__ w_end, const float* __restrict__ b_end,
    int o1, int o2, int hasF, int do_sm, int mode, int widx,
    float* __restrict__ accb, float* __restrict__ out,
    const ushort* __restrict__ gWT, const float* __restrict__ dinv_d,
    const float* __restrict__ dinv_q, ushort* __restrict__ htmp) {
  __shared__ float s_ld[16 * LD_STRIDE];
  __shared__ float s_lq[16 * 16];
  __shared__ float s_red[16 * 8];
  __shared__ __align__(16) ushort s_qw[4 * 16 * 128];  // 16 KB, XOR-swizzled
  int tid = threadIdx.x;
  int wave = tid >> 6, lane = tid & 63;
  int col = lane & 15, quad = lane >> 4;

  if (blockIdx.x >= 128) {  // ---------------- GEMM KD=128 section ----------
    int gblk = blockIdx.x - 128;  // [0,272): data [0,256), query [256,272)
    bool isQ = gblk >= 256;
    int node0;
    if (isQ) node0 = (gblk - 256) * 128;
    else node0 = swz_g(gblk) * 512 + (gblk >> 6) * 128;
    int mloc = node0 + wave * 16;
    const ushort* X = isQ ? qbf : dbf;
    const float* dv = isQ ? dinv_q : dinv_d;
    size_t hbase = isQ ? (size_t)cNd : 0;
    floatx4 acc[8];
#pragma unroll
    for (int ct = 0; ct < 8; ++ct)
#pragma unroll
      for (int r = 0; r < 4; ++r) acc[ct][r] = 0.0f;
#pragma unroll
    for (int kc = 0; kc < 4; ++kc) {
      bf16x8 a = *(const bf16x8*)(X + (size_t)(mloc + col) * 128 + kc * 32 + quad * 8);
#pragma unroll
      for (int ct = 0; ct < 8; ++ct) {
        bf16x8 b = *(const bf16x8*)(gWT + (size_t)(ct * 16 + col) * 128 + kc * 32 + quad * 8);
        acc[ct] = __builtin_amdgcn_mfma_f32_16x16x32_bf16(a, b, acc[ct], 0, 0, 0);
      }
    }
    float sc[4];
#pragma unroll
    for (int r = 0; r < 4; ++r) sc[r] = dv[mloc + quad * 4 + r];
#pragma unroll
    for (int ct = 0; ct < 8; ++ct)
#pragma unroll
      for (int r = 0; r < 4; ++r)
        htmp[(hbase + mloc + quad * 4 + r) * 128 + ct * 16 + col] = f2bf(acc[ct][r] * sc[r]);
    return;
  }

  // ---------------- fused level section ------------------------------------
  int b = swz_g(blockIdx.x & 63);
  int qh = blockIdx.x >> 6;
  int n0 = wave * 64;

  bf16x8 bfr[4][4];
#pragma unroll
  for (int s = 0; s < 4; ++s)
#pragma unroll
    for (int kc = 0; kc < 4; ++kc)
      bfr[s][kc] = *(const bf16x8*)(dbf + ((size_t)(b * 512 + n0 + s * 16 + col) << 7) +
                                    kc * 32 + quad * 8);
  bf16x8 aq[4];
#pragma unroll
  for (int kc = 0; kc < 4; ++kc)
    aq[kc] = *(const bf16x8*)(qbf + (size_t)(b * 32 + qh * 16 + col) * 128 +
                              kc * 32 + quad * 8);

  floatx4 att[4];
#pragma unroll
  for (int s = 0; s < 4; ++s)
#pragma unroll
    for (int r = 0; r < 4; ++r) att[s][r] = 0.0f;
#pragma unroll
  for (int kc = 0; kc < 4; ++kc)
#pragma unroll
    for (int s = 0; s < 4; ++s)
      att[s] = __builtin_amdgcn_mfma_f32_16x16x32_bf16(aq[kc], bfr[s][kc], att[s], 0, 0, 0);
  const float sc = 0.088388347648318440550f;
#pragma unroll
  for (int s = 0; s < 4; ++s)
#pragma unroll
    for (int r = 0; r < 4; ++r) att[s][r] *= sc;

  {
    bf16x8 vn2[4];
#pragma unroll
    for (int kc = 0; kc < 4; ++kc)
      vn2[kc] = *(const bf16x8*)(vnbf + col * 256 + 128 + kc * 32 + quad * 8);
#pragma unroll
    for (int s = 0; s < 4; ++s) {
      floatx4 lda;
#pragma unroll
      for (int r = 0; r < 4; ++r) lda[r] = 0.0f;
#pragma unroll
      for (int kc = 0; kc < 4; ++kc)
        lda = __builtin_amdgcn_mfma_f32_16x16x32_bf16(bfr[s][kc], vn2[kc], lda, 0, 0, 0);
#pragma unroll
      for (int r = 0; r < 4; ++r)
        s_ld[col * LD_STRIDE + n0 + s * 16 + quad * 4 + r] = lda[r];
    }
  }
  if (wave == 0) {
    bf16x8 vn1[4];
#pragma unroll
    for (int kc = 0; kc < 4; ++kc)
      vn1[kc] = *(const bf16x8*)(vnbf + col * 256 + kc * 32 + quad * 8);
    floatx4 lqa;
#pragma unroll
    for (int r = 0; r < 4; ++r) lqa[r] = 0.0f;
#pragma unroll
    for (int kc = 0; kc < 4; ++kc)
      lqa = __builtin_amdgcn_mfma_f32_16x16x32_bf16(aq[kc], vn1[kc], lqa, 0, 0, 0);
#pragma unroll
    for (int r = 0; r < 4; ++r) s_lq[col * 16 + quad * 4 + r] = lqa[r];
  }
  __syncthreads();

  float red[4], M[4];
#pragma unroll
  for (int r = 0; r < 4; ++r) {
    float m = fmaxf(fmaxf(att[0][r], att[1][r]), fmaxf(att[2][r], att[3][r]));
#pragma unroll
    for (int o = 1; o < 16; o <<= 1) m = fmaxf(m, __shfl_xor(m, o, 64));
    red[r] = m;
  }
  if (col == 0)
#pragma unroll
    for (int r = 0; r < 4; ++r) s_red[(quad * 4 + r) * 8 + wave] = red[r];
  __syncthreads();
#pragma unroll
  for (int r = 0; r < 4; ++r) {
    float m = s_red[(quad * 4 + r) * 8];
#pragma unroll
    for (int w = 1; w < 8; ++w) m = fmaxf(m, s_red[(quad * 4 + r) * 8 + w]);
    M[r] = m;
  }
  __syncthreads();
#pragma unroll
  for (int s = 0; s < 4; ++s)
#pragma unroll
    for (int r = 0; r < 4; ++r) att[s][r] = fexp(att[s][r] - M[r]);
#pragma unroll
  for (int r = 0; r < 4; ++r) {
    float m = att[0][r] + att[1][r] + att[2][r] + att[3][r];
#pragma unroll
    for (int o = 1; o < 16; o <<= 1) m += __shfl_xor(m, o, 64);
    red[r] = m;
  }
  if (col == 0)
#pragma unroll
    for (int r = 0; r < 4; ++r) s_red[(quad * 4 + r) * 8 + wave] = red[r];
  __syncthreads();
#pragma unroll
  for (int r = 0; r < 4; ++r) {
    float m = s_red[(quad * 4 + r) * 8];
#pragma unroll
    for (int w = 1; w < 8; ++w) m += s_red[(quad * 4 + r) * 8 + w];
    M[r] = frcp(m);
  }
  __syncthreads();
#pragma unroll
  for (int s = 0; s < 4; ++s)
#pragma unroll
    for (int r = 0; r < 4; ++r) att[s][r] *= M[r];

  floatx4 eacc[4], facc[4];
#pragma unroll
  for (int s = 0; s < 4; ++s)
#pragma unroll
    for (int r = 0; r < 4; ++r) { eacc[s][r] = 0.0f; facc[s][r] = 0.0f; }

  // ---- bil k-loop in 4-k chunks: compute qw slice in LDS, then consume ----
  char* qws = (char*)s_qw;
  const int kk8 = wave >> 1;   // k within chunk handled by this wave
  const int eh = wave & 1;     // e half handled by this wave
  for (int kb = 0; kb < 4; ++kb) {
    int kq = kb * 4 + kk8;
    __syncthreads();  // previous chunk's readers done before overwrite
#pragma unroll
    for (int ei = 0; ei < 4; ++ei) {
      floatx4 qa;
#pragma unroll
      for (int r = 0; r < 4; ++r) qa[r] = 0.0f;
#pragma unroll
      for (int kc = 0; kc < 4; ++kc) {
        bf16x8 bb = *(const bf16x8*)(wnT + (size_t)(kq * 128 + eh * 64 + ei * 16 + col) * 128 +
                                     kc * 32 + quad * 8);
        qa = __builtin_amdgcn_mfma_f32_16x16x32_bf16(aq[kc], bb, qa, 0, 0, 0);
      }
#pragma unroll
      for (int r = 0; r < 4; ++r) {
        int row = quad * 4 + r;
        int byte = (kk8 << 12) + row * 256 + (eh * 64 + ei * 16 + col) * 2;
        byte ^= (row & 7) << 4;
        *(ushort*)(qws + byte) = f2bf(qa[r]);
      }
    }
    __syncthreads();
#pragma unroll
    for (int kj = 0; kj < 4; ++kj) {
      int k = kb * 4 + kj;
      bf16x8 a0, a1, a2, a3;
      {
        int base = (kj << 12) + col * 256 + quad * 16;
        int swz = (col & 7) << 4;
        a0 = *(const bf16x8*)(qws + ((base) ^ swz));
        a1 = *(const bf16x8*)(qws + ((base + 64) ^ swz));
        a2 = *(const bf16x8*)(qws + ((base + 128) ^ swz));
        a3 = *(const bf16x8*)(qws + ((base + 192) ^ swz));
      }
      floatx4 bil[4];
#pragma unroll
      for (int s = 0; s < 4; ++s) {
#pragma unroll
        for (int r = 0; r < 4; ++r) bil[s][r] = 0.0f;
        bil[s] = __builtin_amdgcn_mfma_f32_16x16x32_bf16(a0, bfr[s][0], bil[s], 0, 0, 0);
        bil[s] = __builtin_amdgcn_mfma_f32_16x16x32_bf16(a1, bfr[s][1], bil[s], 0, 0, 0);
        bil[s] = __builtin_amdgcn_mfma_f32_16x16x32_bf16(a2, bfr[s][2], bil[s], 0, 0, 0);
        bil[s] = __builtin_amdgcn_mfma_f32_16x16x32_bf16(a3, bfr[s][3], bil[s], 0, 0, 0);
      }
      float bnk = bn[k], cwk = cw[k];
      float wkk = 0.0f;
      if (hasF) {
        wkk = w_end[o1 + k];
        if (o2 >= 0) wkk += w_end[o2 + k];
      }
      float lqv[4];
#pragma unroll
      for (int r = 0; r < 4; ++r) lqv[r] = s_lq[k * 16 + quad * 4 + r] + bnk;
#pragma unroll
      for (int s = 0; s < 4; ++s) {
        float ldv = s_ld[k * LD_STRIDE + n0 + s * 16 + col];
#pragma unroll
        for (int r = 0; r < 4; ++r) {
          float sg = fsigmoid(bil[s][r] + lqv[r] + ldv);
          eacc[s][r] += cwk * sg;
          facc[s][r] += wkk * sg;
        }
      }
    }
  }

#pragma unroll
  for (int s = 0; s < 4; ++s)
#pragma unroll
    for (int r = 0; r < 4; ++r) {
      eacc[s][r] *= att[s][r];
      facc[s][r] *= att[s][r];
    }
  if (do_sm) {
#pragma unroll
    for (int r = 0; r < 4; ++r) {
      float m = fmaxf(fmaxf(eacc[0][r], eacc[1][r]), fmaxf(eacc[2][r], eacc[3][r]));
#pragma unroll
      for (int o = 1; o < 16; o <<= 1) m = fmaxf(m, __shfl_xor(m, o, 64));
      red[r] = m;
    }
    if (col == 0)
#pragma unroll
      for (int r = 0; r < 4; ++r) s_red[(quad * 4 + r) * 8 + wave] = red[r];
    __syncthreads();
#pragma unroll
    for (int r = 0; r < 4; ++r) {
      float m = s_red[(quad * 4 + r) * 8];
#pragma unroll
      for (int w = 1; w < 8; ++w) m = fmaxf(m, s_red[(quad * 4 + r) * 8 + w]);
      M[r] = m;
    }
    __syncthreads();
#pragma unroll
    for (int s = 0; s < 4; ++s)
#pragma unroll
      for (int r = 0; r < 4; ++r) eacc[s][r] = fexp(eacc[s][r] - M[r]);
#pragma unroll
    for (int r = 0; r < 4; ++r) {
      float m = eacc[0][r] + eacc[1][r] + eacc[2][r] + eacc[3][r];
#pragma unroll
      for (int o = 1; o < 16; o <<= 1) m += __shfl_xor(m, o, 64);
      red[r] = m;
    }
    if (col == 0)
#pragma unroll
      for (int r = 0; r < 4; ++r) s_red[(quad * 4 + r) * 8 + wave] = red[r];
    __syncthreads();
#pragma unroll
    for (int r = 0; r < 4; ++r) {
      float m = s_red[(quad * 4 + r) * 8];
#pragma unroll
      for (int w = 1; w < 8; ++w) m += s_red[(quad * 4 + r) * 8 + w];
      M[r] = frcp(m);
    }
    __syncthreads();
#pragma unroll
    for (int s = 0; s < 4; ++s)
#pragma unroll
      for (int r = 0; r < 4; ++r) eacc[s][r] *= M[r];
  }
  float w = w_end[widx];
#pragma unroll
  for (int s = 0; s < 4; ++s)
#pragma unroll
    for (int r = 0; r < 4; ++r) eacc[s][r] = w * eacc[s][r] + (hasF ? facc[s][r] : 0.0f);

  if (mode == 0) {
#pragma unroll
    for (int s = 0; s < 4; ++s)
#pragma unroll
      for (int r = 0; r < 4; ++r)
        accb[((size_t)(b * 32 + qh * 16 + quad * 4 + r) << 9) + n0 + s * 16 + col] =
            eacc[s][r];
  } else if (mode == 1) {
#pragma unroll
    for (int s = 0; s < 4; ++s)
#pragma unroll
      for (int r = 0; r < 4; ++r)
        accb[((size_t)(b * 32 + qh * 16 + quad * 4 + r) << 9) + n0 + s * 16 + col] +=
            eacc[s][r];
  } else {
    float be = b_end[0];
#pragma unroll
    for (int s = 0; s < 4; ++s)
#pragma unroll
      for (int r = 0; r < 4; ++r)
        eacc[s][r] += accb[((size_t)(b * 32 + qh * 16 + quad * 4 + r) << 9) +
                           n0 + s * 16 + col] + be;
#pragma unroll
    for (int r = 0; r < 4; ++r) {
      float m = fmaxf(fmaxf(eacc[0][r], eacc[1][r]), fmaxf(eacc[2][r], eacc[3][r]));
#pragma unroll
      for (int o = 1; o < 16; o <<= 1) m = fmaxf(m, __shfl_xor(m, o, 64));
      red[r] = m;
    }
    if (col == 0)
#pragma unroll
      for (int r = 0; r < 4; ++r) s_red[(quad * 4 + r) * 8 + wave] = red[r];
    __syncthreads();
#pragma unroll
    for (int r = 0; r < 4; ++r) {
      float m = s_red[(quad * 4 + r) * 8];
#pragma unroll
      for (int w2 = 1; w2 < 8; ++w2) m = fmaxf(m, s_red[(quad * 4 + r) * 8 + w2]);
      M[r] = m;
    }
    __syncthreads();
#pragma unroll
    for (int s = 0; s < 4; ++s)
#pragma unroll
      for (int r = 0; r < 4; ++r) eacc[s][r] = fexp(eacc[s][r] - M[r]);
#pragma unroll
    for (int r = 0; r < 4; ++r) {
      float m = eacc[0][r] + eacc[1][r] + eacc[2][r] + eacc[3][r];
#pragma unroll
      for (int o = 1; o < 16; o <<= 1) m += __shfl_xor(m, o, 64);
      red[r] = m;
    }
    if (col == 0)
#pragma unroll
      for (int r = 0; r < 4; ++r) s_red[(quad * 4 + r) * 8 + wave] = red[r];
    __syncthreads();
#pragma unroll
    for (int r = 0; r < 4; ++r) {
      float m = s_red[(quad * 4 + r) * 8];
#pragma unroll
      for (int w2 = 1; w2 < 8; ++w2) m += s_red[(quad * 4 + r) * 8 + w2];
      M[r] = frcp(m);
    }
#pragma unroll
    for (int s = 0; s < 4; ++s)
#pragma unroll
      for (int r = 0; r < 4; ++r)
        out[((size_t)(b * 32 + qh * 16 + quad * 4 + r) << 9) + n0 + s * 16 + col] =
            eacc[s][r] * M[r];
  }
}

// ---------------------------------------------------------------------------
// Host orchestration — 8 dispatches (no memset, no scan, no fill, no qw)
// ---------------------------------------------------------------------------
extern "C" void kernel_launch(void* const* d_in, const int* in_sizes, int n_in,
                              void* d_out, int out_size, void* d_ws, size_t ws_size,
                              hipStream_t stream) {
  (void)in_sizes; (void)n_in; (void)out_size; (void)ws_size;
  const float* x_d = (const float*)d_in[0];
  const float* x_q = (const float*)d_in[1];
  const int* ei_d = (const int*)d_in[2];
  const int* ei_q = (const int*)d_in[3];
  const float* W1 = (const float*)d_in[6];
  const float* b1 = (const float*)d_in[7];
  const float* W2 = (const float*)d_in[8];
  const float* b2 = (const float*)d_in[9];
  const float* W3 = (const float*)d_in[10];
  const float* b3 = (const float*)d_in[11];
  const float* Wn[3] = {(const float*)d_in[12], (const float*)d_in[17], (const float*)d_in[22]};
  const float* Vn[3] = {(const float*)d_in[13], (const float*)d_in[18], (const float*)d_in[23]};
  const float* bn[3] = {(const float*)d_in[14], (const float*)d_in[19], (const float*)d_in[24]};
  const float* cw[3] = {(const float*)d_in[15], (const float*)d_in[20], (const float*)d_in[25]};
  const float* w_end = (const float*)d_in[27];
  const float* b_end = (const float*)d_in[28];
  float* out = (float*)d_out;

  char* wsp = (char*)d_ws;
  auto alloc = [&](size_t nbytes) {
    void* p = (void*)wsp;
    wsp += (nbytes + 255) & ~(size_t)255;
    return p;
  };
  int* cnt_d = (int*)alloc(cNd * 4);
  int* cnt_q = (int*)alloc(cNq * 4);
  float* dinv_d = (float*)alloc(cNd * 4);
  float* dinv_q = (float*)alloc(cNq * 4);
  int* rp_d = (int*)alloc(cNd * 4);
  int* rp_q = (int*)alloc(cNq * 4);
  int* col_d = (int*)alloc((size_t)cEd * 4);
  int* col_q = (int*)alloc((size_t)cEq * 4);
  ushort* xdbf = (ushort*)alloc((size_t)cNd * 64 * 2);
  ushort* xqbf = (ushort*)alloc((size_t)cNq * 64 * 2);
  ushort* w1T = (ushort*)alloc(128 * 64 * 2);
  ushort* w2T = (ushort*)alloc(128 * 128 * 2);
  ushort* w3T = (ushort*)alloc(128 * 128 * 2);
  ushort* wnT[3];
  for (int l = 0; l < 3; ++l) wnT[l] = (ushort*)alloc((size_t)16 * 128 * 128 * 2);
  ushort* vnbf[3];
  for (int l = 0; l < 3; ++l) vnbf[l] = (ushort*)alloc(16 * 256 * 2);
  ushort* htmp = (ushort*)alloc((size_t)(cNd + cNq) * 128 * 2);
  ushort* dbf = (ushort*)alloc((size_t)cNd * 128 * 2);
  ushort* qbf[3];
  for (int l = 0; l < 3; ++l) qbf[l] = (ushort*)alloc((size_t)cNq * 128 * 2);
  float* accb = (float*)alloc((size_t)cB * cNQ * cND * 4);

  const int* src_d = ei_d;
  const int* dst_d = ei_d + cEd;
  const int* src_q = ei_q;
  const int* dst_q = ei_q + cEq;

  // D1: CSR build (first blocks) + conversions + transposes (no memset needed)
  k_front_csr<<<TR0 + NB_T2BF, 256, 0, stream>>>(
      x_d, x_q, Vn[0], Vn[1], Vn[2], xdbf, xqbf, vnbf[0], vnbf[1], vnbf[2], W1, W2,
      W3, Wn[0], Wn[1], Wn[2], w1T, w2T, w3T, wnT[0], wnT[1], wnT[2],
      src_d, dst_d, src_q, dst_q, cnt_d, cnt_q, rp_d, rp_q, dinv_d, dinv_q,
      col_d, col_q);

  // D2: GEMM layer 1
  k_gemm1<<<544, 256, 0, stream>>>(xdbf, xqbf, w1T, dinv_d, dinv_q, htmp);

  const float* bias[3] = {b1, b2, b3};
  const ushort* nextWT[3] = {w2T, w3T, nullptr};
  const int o1s[3] = {0, 19, 3};
  const int o2s[3] = {-1, -1, 35};
  const int hasF[3] = {0, 1, 1};
  const int dosms[3] = {1, 0, 1};
  const int modes[3] = {0, 1, 2};

  for (int l = 0; l < 3; ++l) {
    // gather layer l -> dbf, qbf[l]
    gmn_gather_merged<<<(cNd + cNq) / 8, 256, 0, stream>>>(
        htmp, rp_d, cnt_d, col_d, dinv_d, rp_q, cnt_q, col_q, dinv_q, bias[l], dbf,
        qbf[l]);
    // fused level l (in-block qW) + GEMM for layer l+1 (co-dispatched)
    int grid = (l < 2) ? (128 + 272) : 128;
    k_level_gemm<<<grid, 512, 0, stream>>>(
        qbf[l], dbf, wnT[l], vnbf[l], bn[l], cw[l], w_end, b_end, o1s[l], o2s[l],
        hasF[l], dosms[l], modes[l], l, accb, out, nextWT[l], dinv_d, dinv_q, htmp);
  }
}

// Round 5
// 304.900 us; speedup vs baseline: 2.2516x; 1.0214x over previous
//
#include <hip/hip_runtime.h>
#include <math.h>

// ---------------------------------------------------------------------------
// Problem constants (fixed production sizes from the reference)
// ---------------------------------------------------------------------------
namespace {
constexpr int cB  = 64;
constexpr int cNQ = 32;
constexpr int cND = 512;
constexpr int cNd = cB * cND;   // 32768
constexpr int cNq = cB * cNQ;   // 2048
constexpr int cEd = cNd * 8;    // 262144 (exactly 4096 per graph, graph-sorted)
constexpr int cEq = cNq * 8;    // 16384  (exactly 256 per graph, graph-sorted)
constexpr int LD_STRIDE = 516;
// front kernel block ranges: CSR first (starts immediately), then cvt/transpose
constexpr int NB_CSRD = 64;                    // [0,64)
constexpr int NB_CSRQ = 8;                     // [64,72)
constexpr int CVT0 = NB_CSRD + NB_CSRQ;        // 72
constexpr int NB_CVT = 2188;                   // [72,2260)
constexpr int TR0 = CVT0 + NB_CVT;             // 2260
constexpr int NB_T2BF = 808;                   // [2260,3068)
}

#define F4C(p) (*(const float4*)(p))

typedef __attribute__((ext_vector_type(8))) __bf16 bf16x8;
typedef __attribute__((ext_vector_type(4))) float floatx4;

__device__ __forceinline__ ushort f2bf(float f) {
  union { float f; unsigned u; } v;
  v.f = f;
  unsigned u = v.u;
  return (ushort)((u + 0x7fffu + ((u >> 16) & 1u)) >> 16);
}
__device__ __forceinline__ float bf2f(ushort u) {
  union { unsigned u; float f; } v;
  v.u = ((unsigned)u) << 16;
  return v.f;
}
__device__ __forceinline__ float4 us4f4(ushort4 u) {
  return make_float4(bf2f(u.x), bf2f(u.y), bf2f(u.z), bf2f(u.w));
}
__device__ __forceinline__ ushort4 f4us4(float4 f) {
  ushort4 o;
  o.x = f2bf(f.x); o.y = f2bf(f.y); o.z = f2bf(f.z); o.w = f2bf(f.w);
  return o;
}
__device__ __forceinline__ float fexp2(float x) {
#if __has_builtin(__builtin_amdgcn_exp2f)
  return __builtin_amdgcn_exp2f(x);
#else
  return exp2f(x);
#endif
}
__device__ __forceinline__ float frcp(float x) {
#if __has_builtin(__builtin_amdgcn_rcpf)
  return __builtin_amdgcn_rcpf(x);
#else
  return 1.0f / x;
#endif
}
__device__ __forceinline__ float fsigmoid(float z) {
  return frcp(1.0f + fexp2(z * -1.4426950408889634f));
}
__device__ __forceinline__ float fexp(float x) { return fexp2(x * 1.4426950408889634f); }

// XCD-affinity swizzle (low 6 bits only)
__device__ __forceinline__ int swz_g(int j) { return (((j >> 3) & 7) << 3) | (j & 7); }

// ---------------------------------------------------------------------------
// D1: per-graph CSR build (blocks FIRST so they start immediately) +
// conversions + weight transposes. grid 3068 x 256.
// ---------------------------------------------------------------------------
__global__ __launch_bounds__(256) void k_front_csr(
    const float* __restrict__ xd, const float* __restrict__ xq,
    const float* __restrict__ v0, const float* __restrict__ v1,
    const float* __restrict__ v2, ushort* __restrict__ oxd, ushort* __restrict__ oxq,
    ushort* __restrict__ ov0, ushort* __restrict__ ov1, ushort* __restrict__ ov2,
    const float* __restrict__ W1, const float* __restrict__ W2,
    const float* __restrict__ W3, const float* __restrict__ Wn0,
    const float* __restrict__ Wn1, const float* __restrict__ Wn2,
    ushort* __restrict__ o1, ushort* __restrict__ o2, ushort* __restrict__ o3,
    ushort* __restrict__ on0, ushort* __restrict__ on1, ushort* __restrict__ on2,
    const int* __restrict__ src_d, const int* __restrict__ dst_d,
    const int* __restrict__ src_q, const int* __restrict__ dst_q,
    int* __restrict__ cnt_d, int* __restrict__ cnt_q,
    int* __restrict__ rp_d, int* __restrict__ rp_q,
    float* __restrict__ dinv_d, float* __restrict__ dinv_q,
    int* __restrict__ col_d, int* __restrict__ col_q) {
  __shared__ float tile[32][33];
  __shared__ int s_cnt[512];
  __shared__ int s_base[512];
  __shared__ int s_cur[512];
  int blk = blockIdx.x, tid = threadIdx.x;
  if (blk < NB_CSRD) {
    // ---------------- per-graph data CSR build (512 nodes, 4096 edges) ------
    int g = blk;
    const int* dstg = dst_d + g * 4096;
    const int* srcg = src_d + g * 4096;
    int nbase = g * 512;
    s_cnt[tid] = 0; s_cnt[tid + 256] = 0;
    __syncthreads();
    for (int e = tid; e < 4096; e += 256) atomicAdd(&s_cnt[dstg[e] - nbase], 1);
    __syncthreads();
    int c0 = s_cnt[tid], c1 = s_cnt[tid + 256];
    s_base[tid] = c0; s_base[tid + 256] = c1;
    __syncthreads();
    // Hillis-Steele inclusive scan over 512 entries with 256 threads
    for (int off = 1; off < 512; off <<= 1) {
      int a = (tid >= off) ? s_base[tid - off] : 0;
      int b = (tid + 256 >= off) ? s_base[tid + 256 - off] : 0;
      __syncthreads();
      s_base[tid] += a; s_base[tid + 256] += b;
      __syncthreads();
    }
    int e0 = s_base[tid] - c0, e1 = s_base[tid + 256] - c1;  // exclusive
    s_base[tid] = e0; s_base[tid + 256] = e1;
    s_cur[tid] = 0; s_cur[tid + 256] = 0;
    cnt_d[nbase + tid] = c0;
    cnt_d[nbase + tid + 256] = c1;
    rp_d[nbase + tid] = g * 4096 + e0;
    rp_d[nbase + tid + 256] = g * 4096 + e1;
    dinv_d[nbase + tid] = 1.0f / sqrtf((float)(c0 + 1));
    dinv_d[nbase + tid + 256] = 1.0f / sqrtf((float)(c1 + 1));
    __syncthreads();
    for (int e = tid; e < 4096; e += 256) {
      int d = dstg[e] - nbase;
      int p = atomicAdd(&s_cur[d], 1);
      col_d[g * 4096 + s_base[d] + p] = srcg[e];
    }
  } else if (blk < CVT0) {
    // ---------------- per-graph query CSR build (8 graphs/block) ------------
    int qb = blk - NB_CSRD;
    int lg = tid >> 5, lane32 = tid & 31;
    int g = qb * 8 + lg;
    const int* dstg = dst_q + g * 256;
    const int* srcg = src_q + g * 256;
    int nbase = g * 32;
    s_cnt[tid] = 0;
    __syncthreads();
#pragma unroll
    for (int j = 0; j < 8; ++j)
      atomicAdd(&s_cnt[lg * 32 + (dstg[lane32 + j * 32] - nbase)], 1);
    __syncthreads();
    int v = s_cnt[tid];
    int incl = v;
#pragma unroll
    for (int off = 1; off < 32; off <<= 1) {
      int t = __shfl_up(incl, off, 32);
      if (lane32 >= off) incl += t;
    }
    int excl = incl - v;
    cnt_q[nbase + lane32] = v;
    rp_q[nbase + lane32] = g * 256 + excl;
    dinv_q[nbase + lane32] = 1.0f / sqrtf((float)(v + 1));
    s_base[tid] = excl;
    s_cur[tid] = 0;
    __syncthreads();
#pragma unroll
    for (int j = 0; j < 8; ++j) {
      int e = lane32 + j * 32;
      int d = dstg[e] - nbase;
      int p = atomicAdd(&s_cur[lg * 32 + d], 1);
      col_q[g * 256 + s_base[lg * 32 + d] + p] = srcg[e];
    }
  } else if (blk < TR0) {
    int b2 = blk - CVT0;
    const float* src;
    ushort* dst;
    int i;
    if (b2 < 2048) { src = xd; dst = oxd; i = b2 * 256 + tid; }
    else if (b2 < 2176) { src = xq; dst = oxq; i = (b2 - 2048) * 256 + tid; }
    else if (b2 < 2180) { src = v0; dst = ov0; i = (b2 - 2176) * 256 + tid; }
    else if (b2 < 2184) { src = v1; dst = ov1; i = (b2 - 2180) * 256 + tid; }
    else { src = v2; dst = ov2; i = (b2 - 2184) * 256 + tid; }
    *(ushort4*)(dst + (size_t)i * 4) = f4us4(F4C(src + (size_t)i * 4));
  } else {
    int b5 = blk - TR0;
    const float* in;
    ushort* out;
    int R, C, bt, t;
    if (b5 < 8)        { in = W1;  out = o1;  R = 64;  C = 128; bt = 0; t = b5; }
    else if (b5 < 24)  { in = W2;  out = o2;  R = 128; C = 128; bt = 0; t = b5 - 8; }
    else if (b5 < 40)  { in = W3;  out = o3;  R = 128; C = 128; bt = 0; t = b5 - 24; }
    else if (b5 < 296) { in = Wn0; out = on0; R = 128; C = 128; bt = (b5 - 40) >> 4;  t = (b5 - 40) & 15; }
    else if (b5 < 552) { in = Wn1; out = on1; R = 128; C = 128; bt = (b5 - 296) >> 4; t = (b5 - 296) & 15; }
    else               { in = Wn2; out = on2; R = 128; C = 128; bt = (b5 - 552) >> 4; t = (b5 - 552) & 15; }
    int tilesC = C >> 5;
    int tr = t / tilesC, tc = t - tr * tilesC;
    int tx = tid & 31, ty = tid >> 5;
    const float* ib = in + (size_t)bt * R * C;
    ushort* ob = out + (size_t)bt * R * C;
#pragma unroll
    for (int i = 0; i < 4; ++i)
      tile[ty + i * 8][tx] = ib[(tr * 32 + ty + i * 8) * C + tc * 32 + tx];
    __syncthreads();
#pragma unroll
    for (int i = 0; i < 4; ++i)
      ob[(size_t)(tc * 32 + ty + i * 8) * R + tr * 32 + tx] = f2bf(tile[tx][ty + i * 8]);
  }
}

// ---------------------------------------------------------------------------
// D2: GCN GEMM layer 1 (KD=64). grid 544 x 256.
// ---------------------------------------------------------------------------
__global__ __launch_bounds__(256) void k_gemm1(
    const ushort* __restrict__ xdbf, const ushort* __restrict__ xqbf,
    const ushort* __restrict__ w1T, const float* __restrict__ dinv_d,
    const float* __restrict__ dinv_q, ushort* __restrict__ htmp) {
  int blk2 = blockIdx.x, tid = threadIdx.x;  // data [0,512) swizzled, query [512,544)
  int wave = tid >> 6, lane = tid & 63;
  int col = lane & 15, quad = lane >> 4;
  bool isQ = blk2 >= 512;
  int node0;
  if (isQ) node0 = (blk2 - 512) * 64;
  else node0 = swz_g(blk2) * 512 + (blk2 >> 6) * 64;
  int mloc = node0 + wave * 16;
  const ushort* X = isQ ? xqbf : xdbf;
  const float* dv = isQ ? dinv_q : dinv_d;
  size_t hbase = isQ ? (size_t)cNd : 0;
  floatx4 acc[8];
#pragma unroll
  for (int ct = 0; ct < 8; ++ct)
#pragma unroll
    for (int r = 0; r < 4; ++r) acc[ct][r] = 0.0f;
#pragma unroll
  for (int kc = 0; kc < 2; ++kc) {
    bf16x8 a = *(const bf16x8*)(X + (size_t)(mloc + col) * 64 + kc * 32 + quad * 8);
#pragma unroll
    for (int ct = 0; ct < 8; ++ct) {
      bf16x8 b = *(const bf16x8*)(w1T + (size_t)(ct * 16 + col) * 64 + kc * 32 + quad * 8);
      acc[ct] = __builtin_amdgcn_mfma_f32_16x16x32_bf16(a, b, acc[ct], 0, 0, 0);
    }
  }
  float sc[4];
#pragma unroll
  for (int r = 0; r < 4; ++r) sc[r] = dv[mloc + quad * 4 + r];
#pragma unroll
  for (int ct = 0; ct < 8; ++ct)
#pragma unroll
    for (int r = 0; r < 4; ++r)
      htmp[(hbase + mloc + quad * 4 + r) * 128 + ct * 16 + col] = f2bf(acc[ct][r] * sc[r]);
}

// ---------------------------------------------------------------------------
// GCN aggregate (byte-identical to R0's verified gmn_gather_merged).
// grid 4352 x 256.
// ---------------------------------------------------------------------------
__global__ __launch_bounds__(256) void gmn_gather_merged(
    const ushort* __restrict__ htmp, const int* __restrict__ rp_d,
    const int* __restrict__ cnt_d, const int* __restrict__ col_d,
    const float* __restrict__ dinv_d, const int* __restrict__ rp_q,
    const int* __restrict__ cnt_q, const int* __restrict__ col_q,
    const float* __restrict__ dinv_q, const float* __restrict__ bias,
    ushort* __restrict__ dbf, ushort* __restrict__ qbf) {
  int blk = blockIdx.x, tid = threadIdx.x;
  bool isQ = blk >= 4096;
  int node;
  if (isQ) {
    int j = blk - 4096;
    node = swz_g(j) * 32 + (j >> 6) * 8 + (tid >> 5);
  } else {
    node = swz_g(blk) * 512 + (blk >> 6) * 8 + (tid >> 5);
  }
  int l = tid & 31;
  const ushort* hs = htmp + (isQ ? (size_t)cNd * 128 : 0);
  const int* rp = isQ ? rp_q : rp_d;
  const int* cnt = isQ ? cnt_q : cnt_d;
  const int* col = isQ ? col_q : col_d;
  const float* dinv = isQ ? dinv_q : dinv_d;
  ushort* outp = isQ ? qbf : dbf;
  int c = cnt[node], s0 = rp[node];
  float dt = dinv[node];
  float4 acc = us4f4(*(const ushort4*)(hs + (size_t)node * 128 + l * 4));
  int cm = c < 32 ? c : 32;
  for (int j0 = 0; j0 < cm; j0 += 8) {
    int ss[8];
    ushort4 v[8];
#pragma unroll
    for (int t = 0; t < 8; ++t) {
      int jj = j0 + t;
      ss[t] = (jj < cm) ? col[s0 + jj] : -1;
    }
#pragma unroll
    for (int t = 0; t < 8; ++t)
      if (ss[t] >= 0) v[t] = *(const ushort4*)(hs + (size_t)ss[t] * 128 + l * 4);
#pragma unroll
    for (int t = 0; t < 8; ++t) {
      if (ss[t] >= 0) {
        float4 f = us4f4(v[t]);
        acc.x += f.x; acc.y += f.y; acc.z += f.z; acc.w += f.w;
      }
    }
  }
  for (int j = 32; j < c; ++j) {
    int s = col[s0 + j];
    float4 f = us4f4(*(const ushort4*)(hs + (size_t)s * 128 + l * 4));
    acc.x += f.x; acc.y += f.y; acc.z += f.z; acc.w += f.w;
  }
  float4 bv = F4C(bias + l * 4);
  float4 r;
  r.x = fmaxf(acc.x * dt + bv.x, 0.0f);
  r.y = fmaxf(acc.y * dt + bv.y, 0.0f);
  r.z = fmaxf(acc.z * dt + bv.z, 0.0f);
  r.w = fmaxf(acc.w * dt + bv.w, 0.0f);
  *(ushort4*)(outp + (size_t)node * 128 + l * 4) = f4us4(r);
}

// ---------------------------------------------------------------------------
// Merged dispatch: fused NTN level WITH in-block qW [blk<128, 512 thr] +
// next-layer GCN GEMM KD=128 [blk in [128,128+272)].
// __launch_bounds__(512,2): 2 blocks/CU so all 400 blocks co-reside and the
// GEMM blocks' MFMA/VMEM hides the level blocks' qW-chain latency (R4's
// (512,1) cost +20us/dispatch: 400 blocks > 256 slots serialized a 2nd wave).
// ---------------------------------------------------------------------------
__global__ __launch_bounds__(512, 2) void k_level_gemm(
    const ushort* __restrict__ qbf, const ushort* __restrict__ dbf,
    const ushort* __restrict__ wnT, const ushort* __restrict__ vnbf,
    const float* __restrict__ bn, const float* __restrict__ cw,
    const float* __restrict__ w_end, const float* __restrict__ b_end,
    int o1, int o2, int hasF, int do_sm, int mode, int widx,
    float* __restrict__ accb, float* __restrict__ out,
    const ushort* __restrict__ gWT, const float* __restrict__ dinv_d,
    const float* __restrict__ dinv_q, ushort* __restrict__ htmp) {
  __shared__ float s_ld[16 * LD_STRIDE];
  __shared__ float s_lq[16 * 16];
  __shared__ float s_red[16 * 8];
  __shared__ __align__(16) ushort s_qw[4 * 16 * 128];  // 16 KB, XOR-swizzled
  int tid = threadIdx.x;
  int wave = tid >> 6, lane = tid & 63;
  int col = lane & 15, quad = lane >> 4;

  if (blockIdx.x >= 128) {  // ---------------- GEMM KD=128 section ----------
    int gblk = blockIdx.x - 128;  // [0,272): data [0,256), query [256,272)
    bool isQ = gblk >= 256;
    int node0;
    if (isQ) node0 = (gblk - 256) * 128;
    else node0 = swz_g(gblk) * 512 + (gblk >> 6) * 128;
    int mloc = node0 + wave * 16;
    const ushort* X = isQ ? qbf : dbf;
    const float* dv = isQ ? dinv_q : dinv_d;
    size_t hbase = isQ ? (size_t)cNd : 0;
    floatx4 acc[8];
#pragma unroll
    for (int ct = 0; ct < 8; ++ct)
#pragma unroll
      for (int r = 0; r < 4; ++r) acc[ct][r] = 0.0f;
#pragma unroll
    for (int kc = 0; kc < 4; ++kc) {
      bf16x8 a = *(const bf16x8*)(X + (size_t)(mloc + col) * 128 + kc * 32 + quad * 8);
#pragma unroll
      for (int ct = 0; ct < 8; ++ct) {
        bf16x8 b = *(const bf16x8*)(gWT + (size_t)(ct * 16 + col) * 128 + kc * 32 + quad * 8);
        acc[ct] = __builtin_amdgcn_mfma_f32_16x16x32_bf16(a, b, acc[ct], 0, 0, 0);
      }
    }
    float sc[4];
#pragma unroll
    for (int r = 0; r < 4; ++r) sc[r] = dv[mloc + quad * 4 + r];
#pragma unroll
    for (int ct = 0; ct < 8; ++ct)
#pragma unroll
      for (int r = 0; r < 4; ++r)
        htmp[(hbase + mloc + quad * 4 + r) * 128 + ct * 16 + col] = f2bf(acc[ct][r] * sc[r]);
    return;
  }

  // ---------------- fused level section ------------------------------------
  int b = swz_g(blockIdx.x & 63);
  int qh = blockIdx.x >> 6;
  int n0 = wave * 64;

  bf16x8 bfr[4][4];
#pragma unroll
  for (int s = 0; s < 4; ++s)
#pragma unroll
    for (int kc = 0; kc < 4; ++kc)
      bfr[s][kc] = *(const bf16x8*)(dbf + ((size_t)(b * 512 + n0 + s * 16 + col) << 7) +
                                    kc * 32 + quad * 8);
  bf16x8 aq[4];
#pragma unroll
  for (int kc = 0; kc < 4; ++kc)
    aq[kc] = *(const bf16x8*)(qbf + (size_t)(b * 32 + qh * 16 + col) * 128 +
                              kc * 32 + quad * 8);

  floatx4 att[4];
#pragma unroll
  for (int s = 0; s < 4; ++s)
#pragma unroll
    for (int r = 0; r < 4; ++r) att[s][r] = 0.0f;
#pragma unroll
  for (int kc = 0; kc < 4; ++kc)
#pragma unroll
    for (int s = 0; s < 4; ++s)
      att[s] = __builtin_amdgcn_mfma_f32_16x16x32_bf16(aq[kc], bfr[s][kc], att[s], 0, 0, 0);
  const float sc = 0.088388347648318440550f;
#pragma unroll
  for (int s = 0; s < 4; ++s)
#pragma unroll
    for (int r = 0; r < 4; ++r) att[s][r] *= sc;

  {
    bf16x8 vn2[4];
#pragma unroll
    for (int kc = 0; kc < 4; ++kc)
      vn2[kc] = *(const bf16x8*)(vnbf + col * 256 + 128 + kc * 32 + quad * 8);
#pragma unroll
    for (int s = 0; s < 4; ++s) {
      floatx4 lda;
#pragma unroll
      for (int r = 0; r < 4; ++r) lda[r] = 0.0f;
#pragma unroll
      for (int kc = 0; kc < 4; ++kc)
        lda = __builtin_amdgcn_mfma_f32_16x16x32_bf16(bfr[s][kc], vn2[kc], lda, 0, 0, 0);
#pragma unroll
      for (int r = 0; r < 4; ++r)
        s_ld[col * LD_STRIDE + n0 + s * 16 + quad * 4 + r] = lda[r];
    }
  }
  if (wave == 0) {
    bf16x8 vn1[4];
#pragma unroll
    for (int kc = 0; kc < 4; ++kc)
      vn1[kc] = *(const bf16x8*)(vnbf + col * 256 + kc * 32 + quad * 8);
    floatx4 lqa;
#pragma unroll
    for (int r = 0; r < 4; ++r) lqa[r] = 0.0f;
#pragma unroll
    for (int kc = 0; kc < 4; ++kc)
      lqa = __builtin_amdgcn_mfma_f32_16x16x32_bf16(aq[kc], vn1[kc], lqa, 0, 0, 0);
#pragma unroll
    for (int r = 0; r < 4; ++r) s_lq[col * 16 + quad * 4 + r] = lqa[r];
  }
  __syncthreads();

  float red[4], M[4];
#pragma unroll
  for (int r = 0; r < 4; ++r) {
    float m = fmaxf(fmaxf(att[0][r], att[1][r]), fmaxf(att[2][r], att[3][r]));
#pragma unroll
    for (int o = 1; o < 16; o <<= 1) m = fmaxf(m, __shfl_xor(m, o, 64));
    red[r] = m;
  }
  if (col == 0)
#pragma unroll
    for (int r = 0; r < 4; ++r) s_red[(quad * 4 + r) * 8 + wave] = red[r];
  __syncthreads();
#pragma unroll
  for (int r = 0; r < 4; ++r) {
    float m = s_red[(quad * 4 + r) * 8];
#pragma unroll
    for (int w = 1; w < 8; ++w) m = fmaxf(m, s_red[(quad * 4 + r) * 8 + w]);
    M[r] = m;
  }
  __syncthreads();
#pragma unroll
  for (int s = 0; s < 4; ++s)
#pragma unroll
    for (int r = 0; r < 4; ++r) att[s][r] = fexp(att[s][r] - M[r]);
#pragma unroll
  for (int r = 0; r < 4; ++r) {
    float m = att[0][r] + att[1][r] + att[2][r] + att[3][r];
#pragma unroll
    for (int o = 1; o < 16; o <<= 1) m += __shfl_xor(m, o, 64);
    red[r] = m;
  }
  if (col == 0)
#pragma unroll
    for (int r = 0; r < 4; ++r) s_red[(quad * 4 + r) * 8 + wave] = red[r];
  __syncthreads();
#pragma unroll
  for (int r = 0; r < 4; ++r) {
    float m = s_red[(quad * 4 + r) * 8];
#pragma unroll
    for (int w = 1; w < 8; ++w) m += s_red[(quad * 4 + r) * 8 + w];
    M[r] = frcp(m);
  }
  __syncthreads();
#pragma unroll
  for (int s = 0; s < 4; ++s)
#pragma unroll
    for (int r = 0; r < 4; ++r) att[s][r] *= M[r];

  floatx4 eacc[4], facc[4];
#pragma unroll
  for (int s = 0; s < 4; ++s)
#pragma unroll
    for (int r = 0; r < 4; ++r) { eacc[s][r] = 0.0f; facc[s][r] = 0.0f; }

  // ---- bil k-loop in 4-k chunks: compute qw slice in LDS, then consume ----
  char* qws = (char*)s_qw;
  const int kk8 = wave >> 1;   // k within chunk handled by this wave
  const int eh = wave & 1;     // e half handled by this wave
  for (int kb = 0; kb < 4; ++kb) {
    int kq = kb * 4 + kk8;
    __syncthreads();  // previous chunk's readers done before overwrite
#pragma unroll
    for (int ei = 0; ei < 4; ++ei) {
      floatx4 qa;
#pragma unroll
      for (int r = 0; r < 4; ++r) qa[r] = 0.0f;
#pragma unroll
      for (int kc = 0; kc < 4; ++kc) {
        bf16x8 bb = *(const bf16x8*)(wnT + (size_t)(kq * 128 + eh * 64 + ei * 16 + col) * 128 +
                                     kc * 32 + quad * 8);
        qa = __builtin_amdgcn_mfma_f32_16x16x32_bf16(aq[kc], bb, qa, 0, 0, 0);
      }
#pragma unroll
      for (int r = 0; r < 4; ++r) {
        int row = quad * 4 + r;
        int byte = (kk8 << 12) + row * 256 + (eh * 64 + ei * 16 + col) * 2;
        byte ^= (row & 7) << 4;
        *(ushort*)(qws + byte) = f2bf(qa[r]);
      }
    }
    __syncthreads();
#pragma unroll
    for (int kj = 0; kj < 4; ++kj) {
      int k = kb * 4 + kj;
      bf16x8 a0, a1, a2, a3;
      {
        int base = (kj << 12) + col * 256 + quad * 16;
        int swz = (col & 7) << 4;
        a0 = *(const bf16x8*)(qws + ((base) ^ swz));
        a1 = *(const bf16x8*)(qws + ((base + 64) ^ swz));
        a2 = *(const bf16x8*)(qws + ((base + 128) ^ swz));
        a3 = *(const bf16x8*)(qws + ((base + 192) ^ swz));
      }
      floatx4 bil[4];
#pragma unroll
      for (int s = 0; s < 4; ++s) {
#pragma unroll
        for (int r = 0; r < 4; ++r) bil[s][r] = 0.0f;
        bil[s] = __builtin_amdgcn_mfma_f32_16x16x32_bf16(a0, bfr[s][0], bil[s], 0, 0, 0);
        bil[s] = __builtin_amdgcn_mfma_f32_16x16x32_bf16(a1, bfr[s][1], bil[s], 0, 0, 0);
        bil[s] = __builtin_amdgcn_mfma_f32_16x16x32_bf16(a2, bfr[s][2], bil[s], 0, 0, 0);
        bil[s] = __builtin_amdgcn_mfma_f32_16x16x32_bf16(a3, bfr[s][3], bil[s], 0, 0, 0);
      }
      float bnk = bn[k], cwk = cw[k];
      float wkk = 0.0f;
      if (hasF) {
        wkk = w_end[o1 + k];
        if (o2 >= 0) wkk += w_end[o2 + k];
      }
      float lqv[4];
#pragma unroll
      for (int r = 0; r < 4; ++r) lqv[r] = s_lq[k * 16 + quad * 4 + r] + bnk;
#pragma unroll
      for (int s = 0; s < 4; ++s) {
        float ldv = s_ld[k * LD_STRIDE + n0 + s * 16 + col];
#pragma unroll
        for (int r = 0; r < 4; ++r) {
          float sg = fsigmoid(bil[s][r] + lqv[r] + ldv);
          eacc[s][r] += cwk * sg;
          facc[s][r] += wkk * sg;
        }
      }
    }
  }

#pragma unroll
  for (int s = 0; s < 4; ++s)
#pragma unroll
    for (int r = 0; r < 4; ++r) {
      eacc[s][r] *= att[s][r];
      facc[s][r] *= att[s][r];
    }
  if (do_sm) {
#pragma unroll
    for (int r = 0; r < 4; ++r) {
      float m = fmaxf(fmaxf(eacc[0][r], eacc[1][r]), fmaxf(eacc[2][r], eacc[3][r]));
#pragma unroll
      for (int o = 1; o < 16; o <<= 1) m = fmaxf(m, __shfl_xor(m, o, 64));
      red[r] = m;
    }
    if (col == 0)
#pragma unroll
      for (int r = 0; r < 4; ++r) s_red[(quad * 4 + r) * 8 + wave] = red[r];
    __syncthreads();
#pragma unroll
    for (int r = 0; r < 4; ++r) {
      float m = s_red[(quad * 4 + r) * 8];
#pragma unroll
      for (int w = 1; w < 8; ++w) m = fmaxf(m, s_red[(quad * 4 + r) * 8 + w]);
      M[r] = m;
    }
    __syncthreads();
#pragma unroll
    for (int s = 0; s < 4; ++s)
#pragma unroll
      for (int r = 0; r < 4; ++r) eacc[s][r] = fexp(eacc[s][r] - M[r]);
#pragma unroll
    for (int r = 0; r < 4; ++r) {
      float m = eacc[0][r] + eacc[1][r] + eacc[2][r] + eacc[3][r];
#pragma unroll
      for (int o = 1; o < 16; o <<= 1) m += __shfl_xor(m, o, 64);
      red[r] = m;
    }
    if (col == 0)
#pragma unroll
      for (int r = 0; r < 4; ++r) s_red[(quad * 4 + r) * 8 + wave] = red[r];
    __syncthreads();
#pragma unroll
    for (int r = 0; r < 4; ++r) {
      float m = s_red[(quad * 4 + r) * 8];
#pragma unroll
      for (int w = 1; w < 8; ++w) m += s_red[(quad * 4 + r) * 8 + w];
      M[r] = frcp(m);
    }
    __syncthreads();
#pragma unroll
    for (int s = 0; s < 4; ++s)
#pragma unroll
      for (int r = 0; r < 4; ++r) eacc[s][r] *= M[r];
  }
  float w = w_end[widx];
#pragma unroll
  for (int s = 0; s < 4; ++s)
#pragma unroll
    for (int r = 0; r < 4; ++r) eacc[s][r] = w * eacc[s][r] + (hasF ? facc[s][r] : 0.0f);

  if (mode == 0) {
#pragma unroll
    for (int s = 0; s < 4; ++s)
#pragma unroll
      for (int r = 0; r < 4; ++r)
        accb[((size_t)(b * 32 + qh * 16 + quad * 4 + r) << 9) + n0 + s * 16 + col] =
            eacc[s][r];
  } else if (mode == 1) {
#pragma unroll
    for (int s = 0; s < 4; ++s)
#pragma unroll
      for (int r = 0; r < 4; ++r)
        accb[((size_t)(b * 32 + qh * 16 + quad * 4 + r) << 9) + n0 + s * 16 + col] +=
            eacc[s][r];
  } else {
    float be = b_end[0];
#pragma unroll
    for (int s = 0; s < 4; ++s)
#pragma unroll
      for (int r = 0; r < 4; ++r)
        eacc[s][r] += accb[((size_t)(b * 32 + qh * 16 + quad * 4 + r) << 9) +
                           n0 + s * 16 + col] + be;
#pragma unroll
    for (int r = 0; r < 4; ++r) {
      float m = fmaxf(fmaxf(eacc[0][r], eacc[1][r]), fmaxf(eacc[2][r], eacc[3][r]));
#pragma unroll
      for (int o = 1; o < 16; o <<= 1) m = fmaxf(m, __shfl_xor(m, o, 64));
      red[r] = m;
    }
    if (col == 0)
#pragma unroll
      for (int r = 0; r < 4; ++r) s_red[(quad * 4 + r) * 8 + wave] = red[r];
    __syncthreads();
#pragma unroll
    for (int r = 0; r < 4; ++r) {
      float m = s_red[(quad * 4 + r) * 8];
#pragma unroll
      for (int w2 = 1; w2 < 8; ++w2) m = fmaxf(m, s_red[(quad * 4 + r) * 8 + w2]);
      M[r] = m;
    }
    __syncthreads();
#pragma unroll
    for (int s = 0; s < 4; ++s)
#pragma unroll
      for (int r = 0; r < 4; ++r) eacc[s][r] = fexp(eacc[s][r] - M[r]);
#pragma unroll
    for (int r = 0; r < 4; ++r) {
      float m = eacc[0][r] + eacc[1][r] + eacc[2][r] + eacc[3][r];
#pragma unroll
      for (int o = 1; o < 16; o <<= 1) m += __shfl_xor(m, o, 64);
      red[r] = m;
    }
    if (col == 0)
#pragma unroll
      for (int r = 0; r < 4; ++r) s_red[(quad * 4 + r) * 8 + wave] = red[r];
    __syncthreads();
#pragma unroll
    for (int r = 0; r < 4; ++r) {
      float m = s_red[(quad * 4 + r) * 8];
#pragma unroll
      for (int w2 = 1; w2 < 8; ++w2) m += s_red[(quad * 4 + r) * 8 + w2];
      M[r] = frcp(m);
    }
#pragma unroll
    for (int s = 0; s < 4; ++s)
#pragma unroll
      for (int r = 0; r < 4; ++r)
        out[((size_t)(b * 32 + qh * 16 + quad * 4 + r) << 9) + n0 + s * 16 + col] =
            eacc[s][r] * M[r];
  }
}

// ---------------------------------------------------------------------------
// Host orchestration — 8 dispatches (no memset, no scan, no fill, no qw)
// ---------------------------------------------------------------------------
extern "C" void kernel_launch(void* const* d_in, const int* in_sizes, int n_in,
                              void* d_out, int out_size, void* d_ws, size_t ws_size,
                              hipStream_t stream) {
  (void)in_sizes; (void)n_in; (void)out_size; (void)ws_size;
  const float* x_d = (const float*)d_in[0];
  const float* x_q = (const float*)d_in[1];
  const int* ei_d = (const int*)d_in[2];
  const int* ei_q = (const int*)d_in[3];
  const float* W1 = (const float*)d_in[6];
  const float* b1 = (const float*)d_in[7];
  const float* W2 = (const float*)d_in[8];
  const float* b2 = (const float*)d_in[9];
  const float* W3 = (const float*)d_in[10];
  const float* b3 = (const float*)d_in[11];
  const float* Wn[3] = {(const float*)d_in[12], (const float*)d_in[17], (const float*)d_in[22]};
  const float* Vn[3] = {(const float*)d_in[13], (const float*)d_in[18], (const float*)d_in[23]};
  const float* bn[3] = {(const float*)d_in[14], (const float*)d_in[19], (const float*)d_in[24]};
  const float* cw[3] = {(const float*)d_in[15], (const float*)d_in[20], (const float*)d_in[25]};
  const float* w_end = (const float*)d_in[27];
  const float* b_end = (const float*)d_in[28];
  float* out = (float*)d_out;

  char* wsp = (char*)d_ws;
  auto alloc = [&](size_t nbytes) {
    void* p = (void*)wsp;
    wsp += (nbytes + 255) & ~(size_t)255;
    return p;
  };
  int* cnt_d = (int*)alloc(cNd * 4);
  int* cnt_q = (int*)alloc(cNq * 4);
  float* dinv_d = (float*)alloc(cNd * 4);
  float* dinv_q = (float*)alloc(cNq * 4);
  int* rp_d = (int*)alloc(cNd * 4);
  int* rp_q = (int*)alloc(cNq * 4);
  int* col_d = (int*)alloc((size_t)cEd * 4);
  int* col_q = (int*)alloc((size_t)cEq * 4);
  ushort* xdbf = (ushort*)alloc((size_t)cNd * 64 * 2);
  ushort* xqbf = (ushort*)alloc((size_t)cNq * 64 * 2);
  ushort* w1T = (ushort*)alloc(128 * 64 * 2);
  ushort* w2T = (ushort*)alloc(128 * 128 * 2);
  ushort* w3T = (ushort*)alloc(128 * 128 * 2);
  ushort* wnT[3];
  for (int l = 0; l < 3; ++l) wnT[l] = (ushort*)alloc((size_t)16 * 128 * 128 * 2);
  ushort* vnbf[3];
  for (int l = 0; l < 3; ++l) vnbf[l] = (ushort*)alloc(16 * 256 * 2);
  ushort* htmp = (ushort*)alloc((size_t)(cNd + cNq) * 128 * 2);
  ushort* dbf = (ushort*)alloc((size_t)cNd * 128 * 2);
  ushort* qbf[3];
  for (int l = 0; l < 3; ++l) qbf[l] = (ushort*)alloc((size_t)cNq * 128 * 2);
  float* accb = (float*)alloc((size_t)cB * cNQ * cND * 4);

  const int* src_d = ei_d;
  const int* dst_d = ei_d + cEd;
  const int* src_q = ei_q;
  const int* dst_q = ei_q + cEq;

  // D1: CSR build (first blocks) + conversions + transposes (no memset needed)
  k_front_csr<<<TR0 + NB_T2BF, 256, 0, stream>>>(
      x_d, x_q, Vn[0], Vn[1], Vn[2], xdbf, xqbf, vnbf[0], vnbf[1], vnbf[2], W1, W2,
      W3, Wn[0], Wn[1], Wn[2], w1T, w2T, w3T, wnT[0], wnT[1], wnT[2],
      src_d, dst_d, src_q, dst_q, cnt_d, cnt_q, rp_d, rp_q, dinv_d, dinv_q,
      col_d, col_q);

  // D2: GEMM layer 1
  k_gemm1<<<544, 256, 0, stream>>>(xdbf, xqbf, w1T, dinv_d, dinv_q, htmp);

  const float* bias[3] = {b1, b2, b3};
  const ushort* nextWT[3] = {w2T, w3T, nullptr};
  const int o1s[3] = {0, 19, 3};
  const int o2s[3] = {-1, -1, 35};
  const int hasF[3] = {0, 1, 1};
  const int dosms[3] = {1, 0, 1};
  const int modes[3] = {0, 1, 2};

  for (int l = 0; l < 3; ++l) {
    // gather layer l -> dbf, qbf[l]
    gmn_gather_merged<<<(cNd + cNq) / 8, 256, 0, stream>>>(
        htmp, rp_d, cnt_d, col_d, dinv_d, rp_q, cnt_q, col_q, dinv_q, bias[l], dbf,
        qbf[l]);
    // fused level l (in-block qW) + GEMM for layer l+1 (co-dispatched)
    int grid = (l < 2) ? (128 + 272) : 128;
    k_level_gemm<<<grid, 512, 0, stream>>>(
        qbf[l], dbf, wnT[l], vnbf[l], bn[l], cw[l], w_end, b_end, o1s[l], o2s[l],
        hasF[l], dosms[l], modes[l], l, accb, out, nextWT[l], dinv_d, dinv_q, htmp);
  }
}